// Round 6
// baseline (939.662 us; speedup 1.0000x reference)
//
#include <hip/hip_runtime.h>
#include <math.h>

#define NHID 64
#define NPB 256          // nodes per bucket (power of two; local id = node & 255)
#define NPB_SHIFT 8
#define MAXB 512         // supports N up to 131072
#define CAP 10240        // entries per bucket region (mean 8184 @ E=3.2M, +23 sigma)
#define CHUNK 8192       // edges per k_bucketA block

// ---------------------------------------------------------------------------
// K_A: two-level bucketing of both endpoints. One block per 8192-edge chunk.
// LDS histogram over coarse buckets -> ONE global atomic per (block,bucket)
// reserves a contiguous slice -> LDS-rank scatter of packed (payload<<8|local)
// entries. Global atomics: ~300K total.
// ---------------------------------------------------------------------------
__global__ __launch_bounds__(256) void k_bucketA(const int* __restrict__ src,
                                                 const int* __restrict__ dst,
                                                 unsigned int* __restrict__ buf0,  // keyed by dst, payload src
                                                 unsigned int* __restrict__ buf1,  // keyed by src, payload dst
                                                 int* __restrict__ btail0,
                                                 int* __restrict__ btail1,
                                                 int E, int nB) {
    __shared__ int h0[MAXB], h1[MAXB], b0[MAXB], b1[MAXB];
    int tid = threadIdx.x;
    for (int i = tid; i < nB; i += 256) { h0[i] = 0; h1[i] = 0; }
    __syncthreads();
    int e0 = blockIdx.x * CHUNK;
    for (int i = tid; i < CHUNK; i += 256) {
        int e = e0 + i;
        if (e < E) {
            atomicAdd(&h0[dst[e] >> NPB_SHIFT], 1);
            atomicAdd(&h1[src[e] >> NPB_SHIFT], 1);
        }
    }
    __syncthreads();
    for (int i = tid; i < nB; i += 256) {
        int c0 = h0[i], c1 = h1[i];
        b0[i] = c0 ? atomicAdd(&btail0[i], c0) : 0;
        b1[i] = c1 ? atomicAdd(&btail1[i], c1) : 0;
        h0[i] = 0; h1[i] = 0;       // reuse as rank counters
    }
    __syncthreads();
    for (int i = tid; i < CHUNK; i += 256) {
        int e = e0 + i;
        if (e < E) {
            int d = dst[e], s = src[e];
            int bb = d >> NPB_SHIFT;
            int r = atomicAdd(&h0[bb], 1) + b0[bb];
            if (r < CAP)
                buf0[(size_t)bb * CAP + r] = ((unsigned)s << NPB_SHIFT) | (unsigned)(d & (NPB - 1));
            bb = s >> NPB_SHIFT;
            r = atomicAdd(&h1[bb], 1) + b1[bb];
            if (r < CAP)
                buf1[(size_t)bb * CAP + r] = ((unsigned)d << NPB_SHIFT) | (unsigned)(s & (NPB - 1));
        }
    }
}

// ---------------------------------------------------------------------------
// K_B: single-block exclusive scan of per-bucket sizes (both sides).
// ---------------------------------------------------------------------------
__global__ __launch_bounds__(512) void k_bscan(const int* __restrict__ btail0,
                                               const int* __restrict__ btail1,
                                               int* __restrict__ boff0, int* __restrict__ boff1,
                                               int* __restrict__ off0, int* __restrict__ off1,
                                               int nB, int N) {
    __shared__ int sd[512];
    int tid = threadIdx.x;
    int v = (tid < nB) ? min(btail0[tid], CAP) : 0;
    sd[tid] = v; __syncthreads();
    for (int o = 1; o < 512; o <<= 1) {
        int t = (tid >= o) ? sd[tid - o] : 0; __syncthreads();
        sd[tid] += t; __syncthreads();
    }
    if (tid < nB) boff0[tid] = sd[tid] - v;
    if (tid == 511) off0[N] = sd[511];
    __syncthreads();
    v = (tid < nB) ? min(btail1[tid], CAP) : 0;
    sd[tid] = v; __syncthreads();
    for (int o = 1; o < 512; o <<= 1) {
        int t = (tid >= o) ? sd[tid - o] : 0; __syncthreads();
        sd[tid] += t; __syncthreads();
    }
    if (tid < nB) boff1[tid] = sd[tid] - v;
    if (tid == 511) off1[N] = sd[511];
}

// ---------------------------------------------------------------------------
// K_C: per (side,bucket) workgroup: LDS count -> LDS scan -> emit off[] ->
// LDS-atomic rank scatter into the bucket's csr window. Zero global atomics.
// ---------------------------------------------------------------------------
__global__ __launch_bounds__(256) void k_bucket_csr(const unsigned int* __restrict__ buf0,
                                                    const unsigned int* __restrict__ buf1,
                                                    const int* __restrict__ btail0,
                                                    const int* __restrict__ btail1,
                                                    const int* __restrict__ boff0,
                                                    const int* __restrict__ boff1,
                                                    int* __restrict__ off0, int* __restrict__ off1,
                                                    int* __restrict__ csr0, int* __restrict__ csr1,
                                                    int N) {
    int side = blockIdx.x & 1;
    int b = blockIdx.x >> 1;
    const unsigned int* buf = (side ? buf1 : buf0) + (size_t)b * CAP;
    int cnt_b = min((side ? btail1 : btail0)[b], CAP);
    int boff  = (side ? boff1 : boff0)[b];
    int* off  = side ? off1 : off0;
    int* csr  = side ? csr1 : csr0;
    __shared__ int cnt[NPB];
    __shared__ int scn[NPB];
    __shared__ int cur[NPB];
    int tid = threadIdx.x;          // blockDim == NPB == 256
    cnt[tid] = 0;
    __syncthreads();
    for (int i = tid; i < cnt_b; i += 256)
        atomicAdd(&cnt[buf[i] & (NPB - 1)], 1);
    __syncthreads();
    int v = cnt[tid];
    scn[tid] = v; __syncthreads();
    for (int o = 1; o < 256; o <<= 1) {
        int t = (tid >= o) ? scn[tid - o] : 0; __syncthreads();
        scn[tid] += t; __syncthreads();
    }
    int base = boff + scn[tid] - v;   // exclusive
    cur[tid] = base;
    int node = (b << NPB_SHIFT) + tid;
    if (node < N) off[node] = base;
    __syncthreads();
    for (int i = tid; i < cnt_b; i += 256) {
        unsigned int u = buf[i];
        int pos = atomicAdd(&cur[u & (NPB - 1)], 1);
        csr[pos] = (int)(u >> NPB_SHIFT);
    }
}

// ---------------------------------------------------------------------------
// K4: agg[n,:] = mean over in-edges of X[src,:].
// Wave = 4 row-groups x 16 float4-columns; 4 dwordx4 loads (16 edges) in
// flight per wave for MLP. Tail slots masked by 0/1 multiplier.
// ---------------------------------------------------------------------------
__global__ __launch_bounds__(256) void k_agg(const float* __restrict__ X,
                                             const int* __restrict__ off_dst,
                                             const int* __restrict__ csr_dst,
                                             float* __restrict__ agg, int N) {
    int lane = threadIdx.x & 63;
    int node = blockIdx.x * 4 + (threadIdx.x >> 6);
    if (node >= N) return;
    int grp = lane >> 4, col = lane & 15;
    const float4* Xv = (const float4*)X;
    int s0 = off_dst[node], s1 = off_dst[node + 1];
    float4 acc = make_float4(0.f, 0.f, 0.f, 0.f);
    for (int base = s0; base < s1; base += 64) {
        int cnt = min(64, s1 - base);
        int idx = (base + lane < s1) ? csr_dst[base + lane] : 0;
        for (int j = 0; j < cnt; j += 16) {
            int q0 = j + grp, q1 = j + 4 + grp, q2 = j + 8 + grp, q3 = j + 12 + grp;
            int m0 = __shfl(idx, q0);
            int m1 = __shfl(idx, q1);
            int m2 = __shfl(idx, q2);
            int m3 = __shfl(idx, q3);
            float f0 = (q0 < cnt) ? 1.f : 0.f; if (q0 >= cnt) m0 = 0;
            float f1 = (q1 < cnt) ? 1.f : 0.f; if (q1 >= cnt) m1 = 0;
            float f2 = (q2 < cnt) ? 1.f : 0.f; if (q2 >= cnt) m2 = 0;
            float f3 = (q3 < cnt) ? 1.f : 0.f; if (q3 >= cnt) m3 = 0;
            float4 x0 = Xv[(size_t)m0 * 16 + col];
            float4 x1 = Xv[(size_t)m1 * 16 + col];
            float4 x2 = Xv[(size_t)m2 * 16 + col];
            float4 x3 = Xv[(size_t)m3 * 16 + col];
            acc.x += f0 * x0.x; acc.y += f0 * x0.y; acc.z += f0 * x0.z; acc.w += f0 * x0.w;
            acc.x += f1 * x1.x; acc.y += f1 * x1.y; acc.z += f1 * x1.z; acc.w += f1 * x1.w;
            acc.x += f2 * x2.x; acc.y += f2 * x2.y; acc.z += f2 * x2.z; acc.w += f2 * x2.w;
            acc.x += f3 * x3.x; acc.y += f3 * x3.y; acc.z += f3 * x3.z; acc.w += f3 * x3.w;
        }
    }
    acc.x += __shfl_xor(acc.x, 16); acc.y += __shfl_xor(acc.y, 16);
    acc.z += __shfl_xor(acc.z, 16); acc.w += __shfl_xor(acc.w, 16);
    acc.x += __shfl_xor(acc.x, 32); acc.y += __shfl_xor(acc.y, 32);
    acc.z += __shfl_xor(acc.z, 32); acc.w += __shfl_xor(acc.w, 32);
    if (grp == 0) {
        int deg = s1 - s0;
        float inv = 1.f / (float)max(deg, 1);
        float4 r = make_float4(acc.x * inv, acc.y * inv, acc.z * inv, acc.w * inv);
        ((float4*)agg)[(size_t)node * 16 + col] = r;
    }
}

// ---------------------------------------------------------------------------
// K5a: X2 = relu(X·Wself + agg·Wneigh + b). 4 threads per node, 16 output
// columns each -> accumulator = 4 named float4 (16 VGPRs, cannot spill).
// Weights L1-resident (32KB); FMA:VMEM ~ 4:1. In-place X2-over-agg is safe:
// a node's 4 threads share one wave and every store value data-depends on
// all row loads (agg/X2 deliberately NOT restrict-qualified).
// ---------------------------------------------------------------------------
__global__ __launch_bounds__(256) void k_phaseA(const float* __restrict__ X,
                                                const float* agg,
                                                const float* __restrict__ Ws,
                                                const float* __restrict__ Wn,
                                                const float* __restrict__ bconv,
                                                float* X2, int N) {
    int gid = blockIdx.x * 256 + threadIdx.x;
    int n = gid >> 2;
    if (n >= N) return;
    int wb = (gid & 3) << 2;            // float4 index of column base (cg/4)
    const float4* Xv  = (const float4*)(X + (size_t)n * NHID);
    const float4* Gv  = (const float4*)(agg + (size_t)n * NHID);
    const float4* Wsv = (const float4*)Ws;   // row k -> float4s [k*16 .. k*16+15]
    const float4* Wnv = (const float4*)Wn;
    const float4* bv  = (const float4*)bconv;
    float4 a0 = bv[wb], a1 = bv[wb + 1], a2 = bv[wb + 2], a3 = bv[wb + 3];
    #pragma unroll 2
    for (int q = 0; q < 16; ++q) {
        float4 xq = Xv[q];
        float4 gq = Gv[q];
        float xs[4] = {xq.x, xq.y, xq.z, xq.w};
        float gs[4] = {gq.x, gq.y, gq.z, gq.w};
        #pragma unroll
        for (int j = 0; j < 4; ++j) {
            int k16 = (4 * q + j) * 16 + wb;
            float4 w0 = Wsv[k16], w1 = Wsv[k16 + 1], w2 = Wsv[k16 + 2], w3 = Wsv[k16 + 3];
            float4 m0 = Wnv[k16], m1 = Wnv[k16 + 1], m2 = Wnv[k16 + 2], m3 = Wnv[k16 + 3];
            float xj = xs[j], gj = gs[j];
            a0.x += xj * w0.x + gj * m0.x; a0.y += xj * w0.y + gj * m0.y;
            a0.z += xj * w0.z + gj * m0.z; a0.w += xj * w0.w + gj * m0.w;
            a1.x += xj * w1.x + gj * m1.x; a1.y += xj * w1.y + gj * m1.y;
            a1.z += xj * w1.z + gj * m1.z; a1.w += xj * w1.w + gj * m1.w;
            a2.x += xj * w2.x + gj * m2.x; a2.y += xj * w2.y + gj * m2.y;
            a2.z += xj * w2.z + gj * m2.z; a2.w += xj * w2.w + gj * m2.w;
            a3.x += xj * w3.x + gj * m3.x; a3.y += xj * w3.y + gj * m3.y;
            a3.z += xj * w3.z + gj * m3.z; a3.w += xj * w3.w + gj * m3.w;
        }
    }
    float4* out = (float4*)(X2 + (size_t)n * NHID);
    out[wb]     = make_float4(fmaxf(a0.x, 0.f), fmaxf(a0.y, 0.f), fmaxf(a0.z, 0.f), fmaxf(a0.w, 0.f));
    out[wb + 1] = make_float4(fmaxf(a1.x, 0.f), fmaxf(a1.y, 0.f), fmaxf(a1.z, 0.f), fmaxf(a1.w, 0.f));
    out[wb + 2] = make_float4(fmaxf(a2.x, 0.f), fmaxf(a2.y, 0.f), fmaxf(a2.z, 0.f), fmaxf(a2.w, 0.f));
    out[wb + 3] = make_float4(fmaxf(a3.x, 0.f), fmaxf(a3.y, 0.f), fmaxf(a3.z, 0.f), fmaxf(a3.w, 0.f));
}

// ---------------------------------------------------------------------------
// K5b: [a|b] = X2 · [A|B] (+[Qb|0]). 8 threads per node, 16 of the 128
// combined output columns each. A[f][h*16+d]=Qw[h*2048+f*16+d];
// B[f][h*16+d]=Qw[h*2048+(64+f)*16+d].
// ---------------------------------------------------------------------------
__global__ __launch_bounds__(256) void k_phaseB(const float* __restrict__ X2,
                                                const float* __restrict__ Qw,
                                                const float* __restrict__ Qb,
                                                float* __restrict__ aOut,
                                                float* __restrict__ bOut, int N) {
    int gid = blockIdx.x * 256 + threadIdx.x;
    int n = gid >> 3;
    if (n >= N) return;
    int cg = (gid & 7) << 4;            // 0..112
    int isB = (cg >= 64) ? 1 : 0;
    int h = (cg & 63) >> 4;
    const float4* Wv = (const float4*)(Qw + h * 2048 + (isB ? 1024 : 0));  // row f -> Wv[f*4 .. f*4+3]
    float4 a0, a1, a2, a3;
    if (isB) {
        a0 = a1 = a2 = a3 = make_float4(0.f, 0.f, 0.f, 0.f);
    } else {
        const float4* qv = (const float4*)Qb;
        int qb = cg >> 2;
        a0 = qv[qb]; a1 = qv[qb + 1]; a2 = qv[qb + 2]; a3 = qv[qb + 3];
    }
    const float4* Xv = (const float4*)(X2 + (size_t)n * NHID);
    #pragma unroll 2
    for (int q = 0; q < 16; ++q) {
        float4 xq = Xv[q];
        float xs[4] = {xq.x, xq.y, xq.z, xq.w};
        #pragma unroll
        for (int j = 0; j < 4; ++j) {
            int f4 = (4 * q + j) * 4;
            float4 w0 = Wv[f4], w1 = Wv[f4 + 1], w2 = Wv[f4 + 2], w3 = Wv[f4 + 3];
            float xj = xs[j];
            a0.x += xj * w0.x; a0.y += xj * w0.y; a0.z += xj * w0.z; a0.w += xj * w0.w;
            a1.x += xj * w1.x; a1.y += xj * w1.y; a1.z += xj * w1.z; a1.w += xj * w1.w;
            a2.x += xj * w2.x; a2.y += xj * w2.y; a2.z += xj * w2.z; a2.w += xj * w2.w;
            a3.x += xj * w3.x; a3.y += xj * w3.y; a3.z += xj * w3.z; a3.w += xj * w3.w;
        }
    }
    float* outp = isB ? (bOut + (size_t)n * NHID + (cg - 64)) : (aOut + (size_t)n * NHID + cg);
    ((float4*)outp)[0] = a0; ((float4*)outp)[1] = a1;
    ((float4*)outp)[2] = a2; ((float4*)outp)[3] = a3;
}

// ---------------------------------------------------------------------------
// K6: gg[n,:] = tanh(mean over out-edges of (a[n,:] + b[dst,:])^2)
// Same 16-edges-in-flight structure as K4.
// ---------------------------------------------------------------------------
__global__ __launch_bounds__(256) void k_final(const float* __restrict__ aF,
                                               const float* __restrict__ bF,
                                               const int* __restrict__ off_src,
                                               const int* __restrict__ csr_src,
                                               float* __restrict__ out, int N) {
    int lane = threadIdx.x & 63;
    int node = blockIdx.x * 4 + (threadIdx.x >> 6);
    if (node >= N) return;
    int grp = lane >> 4, col = lane & 15;
    const float4* Bv = (const float4*)bF;
    float4 av = ((const float4*)aF)[(size_t)node * 16 + col];
    int s0 = off_src[node], s1 = off_src[node + 1];
    float4 acc = make_float4(0.f, 0.f, 0.f, 0.f);
    for (int base = s0; base < s1; base += 64) {
        int cnt = min(64, s1 - base);
        int idx = (base + lane < s1) ? csr_src[base + lane] : 0;
        for (int j = 0; j < cnt; j += 16) {
            int q0 = j + grp, q1 = j + 4 + grp, q2 = j + 8 + grp, q3 = j + 12 + grp;
            int m0 = __shfl(idx, q0);
            int m1 = __shfl(idx, q1);
            int m2 = __shfl(idx, q2);
            int m3 = __shfl(idx, q3);
            float f0 = (q0 < cnt) ? 1.f : 0.f; if (q0 >= cnt) m0 = 0;
            float f1 = (q1 < cnt) ? 1.f : 0.f; if (q1 >= cnt) m1 = 0;
            float f2 = (q2 < cnt) ? 1.f : 0.f; if (q2 >= cnt) m2 = 0;
            float f3 = (q3 < cnt) ? 1.f : 0.f; if (q3 >= cnt) m3 = 0;
            float4 b0 = Bv[(size_t)m0 * 16 + col];
            float4 b1 = Bv[(size_t)m1 * 16 + col];
            float4 b2 = Bv[(size_t)m2 * 16 + col];
            float4 b3 = Bv[(size_t)m3 * 16 + col];
            float t;
            t = av.x + b0.x; acc.x += f0 * t * t;
            t = av.y + b0.y; acc.y += f0 * t * t;
            t = av.z + b0.z; acc.z += f0 * t * t;
            t = av.w + b0.w; acc.w += f0 * t * t;
            t = av.x + b1.x; acc.x += f1 * t * t;
            t = av.y + b1.y; acc.y += f1 * t * t;
            t = av.z + b1.z; acc.z += f1 * t * t;
            t = av.w + b1.w; acc.w += f1 * t * t;
            t = av.x + b2.x; acc.x += f2 * t * t;
            t = av.y + b2.y; acc.y += f2 * t * t;
            t = av.z + b2.z; acc.z += f2 * t * t;
            t = av.w + b2.w; acc.w += f2 * t * t;
            t = av.x + b3.x; acc.x += f3 * t * t;
            t = av.y + b3.y; acc.y += f3 * t * t;
            t = av.z + b3.z; acc.z += f3 * t * t;
            t = av.w + b3.w; acc.w += f3 * t * t;
        }
    }
    acc.x += __shfl_xor(acc.x, 16); acc.y += __shfl_xor(acc.y, 16);
    acc.z += __shfl_xor(acc.z, 16); acc.w += __shfl_xor(acc.w, 16);
    acc.x += __shfl_xor(acc.x, 32); acc.y += __shfl_xor(acc.y, 32);
    acc.z += __shfl_xor(acc.z, 32); acc.w += __shfl_xor(acc.w, 32);
    if (grp == 0) {
        int deg = s1 - s0;
        float inv = 1.f / (float)max(deg, 1);
        float4 r = make_float4(tanhf(acc.x * inv), tanhf(acc.y * inv),
                               tanhf(acc.z * inv), tanhf(acc.w * inv));
        ((float4*)out)[(size_t)node * 16 + col] = r;
    }
}

// ---------------------------------------------------------------------------
extern "C" void kernel_launch(void* const* d_in, const int* in_sizes, int n_in,
                              void* d_out, int out_size, void* d_ws, size_t ws_size,
                              hipStream_t stream) {
    const float* X      = (const float*)d_in[0];
    const int*   ei     = (const int*)d_in[1];
    const float* Wself  = (const float*)d_in[2];
    const float* Wneigh = (const float*)d_in[3];
    const float* bconv  = (const float*)d_in[4];
    const float* Qw     = (const float*)d_in[5];
    const float* Qb     = (const float*)d_in[6];

    int N = in_sizes[0] / NHID;
    int E = in_sizes[1] / 2;
    const int* src = ei;        // edge_index[0]
    const int* dst = ei + E;    // edge_index[1]
    int nB = (N + NPB - 1) >> NPB_SHIFT;           // 391 for N=100K
    int nChunks = (E + CHUNK - 1) / CHUNK;         // 391 for E=3.2M

    // ---- workspace layout (~103 MB) ----
    char* ws = (char*)d_ws;
    size_t bufBytes = (size_t)MAXB * CAP * 4;      // 21.0 MB per side
    unsigned int* buf0 = (unsigned int*)(ws);
    unsigned int* buf1 = (unsigned int*)(ws + bufBytes);
    float* aggF = (float*)(ws);                                   // after build
    float* aF   = (float*)(ws + (size_t)N * NHID * 4);
    float* bF   = (float*)(ws + (size_t)2 * N * NHID * 4);
    size_t pos = (size_t)3 * N * NHID * 4;
    if (pos < 2 * bufBytes) pos = 2 * bufBytes;
    pos = (pos + 255) & ~(size_t)255;
    auto alloc = [&](size_t bytes) -> void* {
        void* p = ws + pos;
        pos = (pos + bytes + 255) & ~(size_t)255;
        return p;
    };
    int* csr0   = (int*)alloc((size_t)E * 4);      // by dst
    int* csr1   = (int*)alloc((size_t)E * 4);      // by src
    int* off0   = (int*)alloc((size_t)(N + 1) * 4);
    int* off1   = (int*)alloc((size_t)(N + 1) * 4);
    int* btail0 = (int*)alloc((size_t)MAXB * 4);
    int* btail1 = (int*)alloc((size_t)MAXB * 4);
    int* boff0  = (int*)alloc((size_t)MAXB * 4);
    int* boff1  = (int*)alloc((size_t)MAXB * 4);
    (void)ws_size; (void)n_in; (void)out_size;

    hipMemsetAsync(btail0, 0, (size_t)2 * MAXB * 4, stream);   // btail0+btail1 contiguous

    k_bucketA<<<nChunks, 256, 0, stream>>>(src, dst, buf0, buf1, btail0, btail1, E, nB);
    k_bscan<<<1, 512, 0, stream>>>(btail0, btail1, boff0, boff1, off0, off1, nB, N);
    k_bucket_csr<<<nB * 2, 256, 0, stream>>>(buf0, buf1, btail0, btail1,
                                             boff0, boff1, off0, off1, csr0, csr1, N);
    k_agg<<<(N + 3) / 4, 256, 0, stream>>>(X, off0, csr0, aggF, N);
    k_phaseA<<<(N * 4 + 255) / 256, 256, 0, stream>>>(X, aggF, Wself, Wneigh, bconv, aggF, N);
    k_phaseB<<<(N * 8 + 255) / 256, 256, 0, stream>>>(aggF, Qw, Qb, aF, bF, N);
    k_final<<<(N + 3) / 4, 256, 0, stream>>>(aF, bF, off1, csr1, (float*)d_out, N);
}

// Round 7
// 452.293 us; speedup vs baseline: 2.0775x; 2.0775x over previous
//
#include <hip/hip_runtime.h>
#include <math.h>

#define NHID 64
#define NPB 256          // nodes per bucket (power of two; local id = node & 255)
#define NPB_SHIFT 8
#define MAXB 512         // supports N up to 131072
#define CAP 10240        // entries per bucket region (mean 8184 @ E=3.2M, +23 sigma)
#define CHUNK 8192       // edges per k_bucketA block

// ---------------------------------------------------------------------------
// K_A: two-level bucketing of both endpoints. One block per 8192-edge chunk.
// LDS histogram over coarse buckets -> ONE global atomic per (block,bucket)
// reserves a contiguous slice -> LDS-rank scatter of packed (payload<<8|local)
// entries. Global atomics: ~300K total.
// ---------------------------------------------------------------------------
__global__ __launch_bounds__(256) void k_bucketA(const int* __restrict__ src,
                                                 const int* __restrict__ dst,
                                                 unsigned int* __restrict__ buf0,  // keyed by dst, payload src
                                                 unsigned int* __restrict__ buf1,  // keyed by src, payload dst
                                                 int* __restrict__ btail0,
                                                 int* __restrict__ btail1,
                                                 int E, int nB) {
    __shared__ int h0[MAXB], h1[MAXB], b0[MAXB], b1[MAXB];
    int tid = threadIdx.x;
    for (int i = tid; i < nB; i += 256) { h0[i] = 0; h1[i] = 0; }
    __syncthreads();
    int e0 = blockIdx.x * CHUNK;
    for (int i = tid; i < CHUNK; i += 256) {
        int e = e0 + i;
        if (e < E) {
            atomicAdd(&h0[dst[e] >> NPB_SHIFT], 1);
            atomicAdd(&h1[src[e] >> NPB_SHIFT], 1);
        }
    }
    __syncthreads();
    for (int i = tid; i < nB; i += 256) {
        int c0 = h0[i], c1 = h1[i];
        b0[i] = c0 ? atomicAdd(&btail0[i], c0) : 0;
        b1[i] = c1 ? atomicAdd(&btail1[i], c1) : 0;
        h0[i] = 0; h1[i] = 0;       // reuse as rank counters
    }
    __syncthreads();
    for (int i = tid; i < CHUNK; i += 256) {
        int e = e0 + i;
        if (e < E) {
            int d = dst[e], s = src[e];
            int bb = d >> NPB_SHIFT;
            int r = atomicAdd(&h0[bb], 1) + b0[bb];
            if (r < CAP)
                buf0[(size_t)bb * CAP + r] = ((unsigned)s << NPB_SHIFT) | (unsigned)(d & (NPB - 1));
            bb = s >> NPB_SHIFT;
            r = atomicAdd(&h1[bb], 1) + b1[bb];
            if (r < CAP)
                buf1[(size_t)bb * CAP + r] = ((unsigned)d << NPB_SHIFT) | (unsigned)(s & (NPB - 1));
        }
    }
}

// ---------------------------------------------------------------------------
// K_B: single-block exclusive scan of per-bucket sizes (both sides).
// ---------------------------------------------------------------------------
__global__ __launch_bounds__(512) void k_bscan(const int* __restrict__ btail0,
                                               const int* __restrict__ btail1,
                                               int* __restrict__ boff0, int* __restrict__ boff1,
                                               int* __restrict__ off0, int* __restrict__ off1,
                                               int nB, int N) {
    __shared__ int sd[512];
    int tid = threadIdx.x;
    int v = (tid < nB) ? min(btail0[tid], CAP) : 0;
    sd[tid] = v; __syncthreads();
    for (int o = 1; o < 512; o <<= 1) {
        int t = (tid >= o) ? sd[tid - o] : 0; __syncthreads();
        sd[tid] += t; __syncthreads();
    }
    if (tid < nB) boff0[tid] = sd[tid] - v;
    if (tid == 511) off0[N] = sd[511];
    __syncthreads();
    v = (tid < nB) ? min(btail1[tid], CAP) : 0;
    sd[tid] = v; __syncthreads();
    for (int o = 1; o < 512; o <<= 1) {
        int t = (tid >= o) ? sd[tid - o] : 0; __syncthreads();
        sd[tid] += t; __syncthreads();
    }
    if (tid < nB) boff1[tid] = sd[tid] - v;
    if (tid == 511) off1[N] = sd[511];
}

// ---------------------------------------------------------------------------
// K_C: per (side,bucket) workgroup: LDS count -> LDS scan -> emit off[] ->
// LDS-atomic rank scatter into the bucket's csr window. Zero global atomics.
// ---------------------------------------------------------------------------
__global__ __launch_bounds__(256) void k_bucket_csr(const unsigned int* __restrict__ buf0,
                                                    const unsigned int* __restrict__ buf1,
                                                    const int* __restrict__ btail0,
                                                    const int* __restrict__ btail1,
                                                    const int* __restrict__ boff0,
                                                    const int* __restrict__ boff1,
                                                    int* __restrict__ off0, int* __restrict__ off1,
                                                    int* __restrict__ csr0, int* __restrict__ csr1,
                                                    int N) {
    int side = blockIdx.x & 1;
    int b = blockIdx.x >> 1;
    const unsigned int* buf = (side ? buf1 : buf0) + (size_t)b * CAP;
    int cnt_b = min((side ? btail1 : btail0)[b], CAP);
    int boff  = (side ? boff1 : boff0)[b];
    int* off  = side ? off1 : off0;
    int* csr  = side ? csr1 : csr0;
    __shared__ int cnt[NPB];
    __shared__ int scn[NPB];
    __shared__ int cur[NPB];
    int tid = threadIdx.x;          // blockDim == NPB == 256
    cnt[tid] = 0;
    __syncthreads();
    for (int i = tid; i < cnt_b; i += 256)
        atomicAdd(&cnt[buf[i] & (NPB - 1)], 1);
    __syncthreads();
    int v = cnt[tid];
    scn[tid] = v; __syncthreads();
    for (int o = 1; o < 256; o <<= 1) {
        int t = (tid >= o) ? scn[tid - o] : 0; __syncthreads();
        scn[tid] += t; __syncthreads();
    }
    int base = boff + scn[tid] - v;   // exclusive
    cur[tid] = base;
    int node = (b << NPB_SHIFT) + tid;
    if (node < N) off[node] = base;
    __syncthreads();
    for (int i = tid; i < cnt_b; i += 256) {
        unsigned int u = buf[i];
        int pos = atomicAdd(&cur[u & (NPB - 1)], 1);
        csr[pos] = (int)(u >> NPB_SHIFT);
    }
}

// ---------------------------------------------------------------------------
// K4: agg[n,:] = mean over in-edges of X[src,:].
// Wave = 4 row-groups x 16 float4-columns; 4 dwordx4 loads (16 edges) in
// flight per wave for MLP. Tail slots masked by 0/1 multiplier.
// ---------------------------------------------------------------------------
__global__ __launch_bounds__(256) void k_agg(const float* __restrict__ X,
                                             const int* __restrict__ off_dst,
                                             const int* __restrict__ csr_dst,
                                             float* __restrict__ agg, int N) {
    int lane = threadIdx.x & 63;
    int node = blockIdx.x * 4 + (threadIdx.x >> 6);
    if (node >= N) return;
    int grp = lane >> 4, col = lane & 15;
    const float4* Xv = (const float4*)X;
    int s0 = off_dst[node], s1 = off_dst[node + 1];
    float4 acc = make_float4(0.f, 0.f, 0.f, 0.f);
    for (int base = s0; base < s1; base += 64) {
        int cnt = min(64, s1 - base);
        int idx = (base + lane < s1) ? csr_dst[base + lane] : 0;
        for (int j = 0; j < cnt; j += 16) {
            int q0 = j + grp, q1 = j + 4 + grp, q2 = j + 8 + grp, q3 = j + 12 + grp;
            int m0 = __shfl(idx, q0);
            int m1 = __shfl(idx, q1);
            int m2 = __shfl(idx, q2);
            int m3 = __shfl(idx, q3);
            float f0 = (q0 < cnt) ? 1.f : 0.f; if (q0 >= cnt) m0 = 0;
            float f1 = (q1 < cnt) ? 1.f : 0.f; if (q1 >= cnt) m1 = 0;
            float f2 = (q2 < cnt) ? 1.f : 0.f; if (q2 >= cnt) m2 = 0;
            float f3 = (q3 < cnt) ? 1.f : 0.f; if (q3 >= cnt) m3 = 0;
            float4 x0 = Xv[(size_t)m0 * 16 + col];
            float4 x1 = Xv[(size_t)m1 * 16 + col];
            float4 x2 = Xv[(size_t)m2 * 16 + col];
            float4 x3 = Xv[(size_t)m3 * 16 + col];
            acc.x += f0 * x0.x; acc.y += f0 * x0.y; acc.z += f0 * x0.z; acc.w += f0 * x0.w;
            acc.x += f1 * x1.x; acc.y += f1 * x1.y; acc.z += f1 * x1.z; acc.w += f1 * x1.w;
            acc.x += f2 * x2.x; acc.y += f2 * x2.y; acc.z += f2 * x2.z; acc.w += f2 * x2.w;
            acc.x += f3 * x3.x; acc.y += f3 * x3.y; acc.z += f3 * x3.z; acc.w += f3 * x3.w;
        }
    }
    acc.x += __shfl_xor(acc.x, 16); acc.y += __shfl_xor(acc.y, 16);
    acc.z += __shfl_xor(acc.z, 16); acc.w += __shfl_xor(acc.w, 16);
    acc.x += __shfl_xor(acc.x, 32); acc.y += __shfl_xor(acc.y, 32);
    acc.z += __shfl_xor(acc.z, 32); acc.w += __shfl_xor(acc.w, 32);
    if (grp == 0) {
        int deg = s1 - s0;
        float inv = 1.f / (float)max(deg, 1);
        float4 r = make_float4(acc.x * inv, acc.y * inv, acc.z * inv, acc.w * inv);
        ((float4*)agg)[(size_t)node * 16 + col] = r;
    }
}

// ---------------------------------------------------------------------------
// K5a: X2 = relu(X·Wself + agg·Wneigh + b). Weights staged in LDS (32KB,
// contiguous copy, per-CU -> no L1 set aliasing, broadcast reads free).
// 4 threads/node x 16 cols: acc = 4 named float4 (register-resident, proven).
// In-place X2-over-agg safe: a node's 4 threads share one wave; stores are
// program-ordered after all row loads.
// ---------------------------------------------------------------------------
__global__ __launch_bounds__(256) void k_phaseA(const float* __restrict__ X,
                                                const float* agg,
                                                const float* __restrict__ Ws,
                                                const float* __restrict__ Wn,
                                                const float* __restrict__ bconv,
                                                float* X2, int N) {
    __shared__ float sWs[4096];
    __shared__ float sWn[4096];
    __shared__ float sb[64];
    int tid = threadIdx.x;
    for (int i = tid; i < 4096; i += 256) {
        sWs[i] = Ws[i];
        sWn[i] = Wn[i];
    }
    if (tid < 64) sb[tid] = bconv[tid];
    __syncthreads();

    int n = blockIdx.x * 64 + (tid >> 2);
    if (n >= N) return;
    int wb = (tid & 3) << 2;                 // float4 col-base (cols 16*(tid&3))
    const float4* ws4 = (const float4*)sWs;  // row k -> float4s [k*16 .. k*16+15]
    const float4* wn4 = (const float4*)sWn;
    const float4* bv  = (const float4*)sb;
    const float4* Xv  = (const float4*)(X + (size_t)n * NHID);
    const float4* Gv  = (const float4*)(agg + (size_t)n * NHID);
    float4 a0 = bv[wb], a1 = bv[wb + 1], a2 = bv[wb + 2], a3 = bv[wb + 3];
    #pragma unroll 2
    for (int q = 0; q < 16; ++q) {
        float4 xq = Xv[q];
        float4 gq = Gv[q];
        float xs[4] = {xq.x, xq.y, xq.z, xq.w};
        float gs[4] = {gq.x, gq.y, gq.z, gq.w};
        #pragma unroll
        for (int j = 0; j < 4; ++j) {
            int k16 = (4 * q + j) * 16 + wb;
            float4 w0 = ws4[k16], w1 = ws4[k16 + 1], w2 = ws4[k16 + 2], w3 = ws4[k16 + 3];
            float4 m0 = wn4[k16], m1 = wn4[k16 + 1], m2 = wn4[k16 + 2], m3 = wn4[k16 + 3];
            float xj = xs[j], gj = gs[j];
            a0.x += xj * w0.x + gj * m0.x; a0.y += xj * w0.y + gj * m0.y;
            a0.z += xj * w0.z + gj * m0.z; a0.w += xj * w0.w + gj * m0.w;
            a1.x += xj * w1.x + gj * m1.x; a1.y += xj * w1.y + gj * m1.y;
            a1.z += xj * w1.z + gj * m1.z; a1.w += xj * w1.w + gj * m1.w;
            a2.x += xj * w2.x + gj * m2.x; a2.y += xj * w2.y + gj * m2.y;
            a2.z += xj * w2.z + gj * m2.z; a2.w += xj * w2.w + gj * m2.w;
            a3.x += xj * w3.x + gj * m3.x; a3.y += xj * w3.y + gj * m3.y;
            a3.z += xj * w3.z + gj * m3.z; a3.w += xj * w3.w + gj * m3.w;
        }
    }
    float4* out = (float4*)(X2 + (size_t)n * NHID);
    out[wb]     = make_float4(fmaxf(a0.x, 0.f), fmaxf(a0.y, 0.f), fmaxf(a0.z, 0.f), fmaxf(a0.w, 0.f));
    out[wb + 1] = make_float4(fmaxf(a1.x, 0.f), fmaxf(a1.y, 0.f), fmaxf(a1.z, 0.f), fmaxf(a1.w, 0.f));
    out[wb + 2] = make_float4(fmaxf(a2.x, 0.f), fmaxf(a2.y, 0.f), fmaxf(a2.z, 0.f), fmaxf(a2.w, 0.f));
    out[wb + 3] = make_float4(fmaxf(a3.x, 0.f), fmaxf(a3.y, 0.f), fmaxf(a3.z, 0.f), fmaxf(a3.w, 0.f));
}

// ---------------------------------------------------------------------------
// K_rp: one-shot repack of Qw into W2[64][128] = [A|B] row-major.
// A[f][h*16+d] = Qw[h,f,d]; B[f][h*16+d] = Qw[h,64+f,d].
// ---------------------------------------------------------------------------
__global__ __launch_bounds__(256) void k_repackB(const float* __restrict__ Qw,
                                                 float* __restrict__ W2) {
    int i = blockIdx.x * 256 + threadIdx.x;   // grid covers 8192
    if (i >= 8192) return;
    int f = i >> 7, c = i & 127;
    float v;
    if (c < 64) v = Qw[(c >> 4) * 2048 + f * 16 + (c & 15)];
    else { int cc = c - 64; v = Qw[(cc >> 4) * 2048 + (64 + f) * 16 + (cc & 15)]; }
    W2[i] = v;
}

// ---------------------------------------------------------------------------
// K5b: [a|b] = X2 · W2 (+[Qb|0]). W2 staged in LDS (32KB contiguous).
// 8 threads/node x 16 of 128 combined cols; acc = 4 named float4.
// ---------------------------------------------------------------------------
__global__ __launch_bounds__(256) void k_phaseB(const float* __restrict__ X2,
                                                const float* __restrict__ W2,
                                                const float* __restrict__ Qb,
                                                float* __restrict__ aOut,
                                                float* __restrict__ bOut, int N) {
    __shared__ float sW[8192];
    int tid = threadIdx.x;
    for (int i = tid; i < 8192; i += 256) sW[i] = W2[i];
    __syncthreads();

    int n = blockIdx.x * 32 + (tid >> 3);
    if (n >= N) return;
    int part = tid & 7;                 // 0..3 -> a cols, 4..7 -> b cols
    int wb = part << 2;                 // float4 base within 32-float4 row
    const float4* w4 = (const float4*)sW;   // row f -> w4[f*32 .. f*32+31]
    float4 a0, a1, a2, a3;
    if (part < 4) {
        const float4* qv = (const float4*)Qb;
        a0 = qv[wb]; a1 = qv[wb + 1]; a2 = qv[wb + 2]; a3 = qv[wb + 3];
    } else {
        a0 = a1 = a2 = a3 = make_float4(0.f, 0.f, 0.f, 0.f);
    }
    const float4* Xv = (const float4*)(X2 + (size_t)n * NHID);
    #pragma unroll 2
    for (int q = 0; q < 16; ++q) {
        float4 xq = Xv[q];
        float xs[4] = {xq.x, xq.y, xq.z, xq.w};
        #pragma unroll
        for (int j = 0; j < 4; ++j) {
            int f32b = (4 * q + j) * 32 + wb;
            float4 w0 = w4[f32b], w1 = w4[f32b + 1], w2 = w4[f32b + 2], w3 = w4[f32b + 3];
            float xj = xs[j];
            a0.x += xj * w0.x; a0.y += xj * w0.y; a0.z += xj * w0.z; a0.w += xj * w0.w;
            a1.x += xj * w1.x; a1.y += xj * w1.y; a1.z += xj * w1.z; a1.w += xj * w1.w;
            a2.x += xj * w2.x; a2.y += xj * w2.y; a2.z += xj * w2.z; a2.w += xj * w2.w;
            a3.x += xj * w3.x; a3.y += xj * w3.y; a3.z += xj * w3.z; a3.w += xj * w3.w;
        }
    }
    float4* outp = (part < 4) ? (float4*)(aOut + (size_t)n * NHID) + wb
                              : (float4*)(bOut + (size_t)n * NHID) + (wb - 16);
    outp[0] = a0; outp[1] = a1; outp[2] = a2; outp[3] = a3;
}

// ---------------------------------------------------------------------------
// K6: gg[n,:] = tanh(mean over out-edges of (a[n,:] + b[dst,:])^2)
// Same 16-edges-in-flight structure as K4.
// ---------------------------------------------------------------------------
__global__ __launch_bounds__(256) void k_final(const float* __restrict__ aF,
                                               const float* __restrict__ bF,
                                               const int* __restrict__ off_src,
                                               const int* __restrict__ csr_src,
                                               float* __restrict__ out, int N) {
    int lane = threadIdx.x & 63;
    int node = blockIdx.x * 4 + (threadIdx.x >> 6);
    if (node >= N) return;
    int grp = lane >> 4, col = lane & 15;
    const float4* Bv = (const float4*)bF;
    float4 av = ((const float4*)aF)[(size_t)node * 16 + col];
    int s0 = off_src[node], s1 = off_src[node + 1];
    float4 acc = make_float4(0.f, 0.f, 0.f, 0.f);
    for (int base = s0; base < s1; base += 64) {
        int cnt = min(64, s1 - base);
        int idx = (base + lane < s1) ? csr_src[base + lane] : 0;
        for (int j = 0; j < cnt; j += 16) {
            int q0 = j + grp, q1 = j + 4 + grp, q2 = j + 8 + grp, q3 = j + 12 + grp;
            int m0 = __shfl(idx, q0);
            int m1 = __shfl(idx, q1);
            int m2 = __shfl(idx, q2);
            int m3 = __shfl(idx, q3);
            float f0 = (q0 < cnt) ? 1.f : 0.f; if (q0 >= cnt) m0 = 0;
            float f1 = (q1 < cnt) ? 1.f : 0.f; if (q1 >= cnt) m1 = 0;
            float f2 = (q2 < cnt) ? 1.f : 0.f; if (q2 >= cnt) m2 = 0;
            float f3 = (q3 < cnt) ? 1.f : 0.f; if (q3 >= cnt) m3 = 0;
            float4 b0 = Bv[(size_t)m0 * 16 + col];
            float4 b1 = Bv[(size_t)m1 * 16 + col];
            float4 b2 = Bv[(size_t)m2 * 16 + col];
            float4 b3 = Bv[(size_t)m3 * 16 + col];
            float t;
            t = av.x + b0.x; acc.x += f0 * t * t;
            t = av.y + b0.y; acc.y += f0 * t * t;
            t = av.z + b0.z; acc.z += f0 * t * t;
            t = av.w + b0.w; acc.w += f0 * t * t;
            t = av.x + b1.x; acc.x += f1 * t * t;
            t = av.y + b1.y; acc.y += f1 * t * t;
            t = av.z + b1.z; acc.z += f1 * t * t;
            t = av.w + b1.w; acc.w += f1 * t * t;
            t = av.x + b2.x; acc.x += f2 * t * t;
            t = av.y + b2.y; acc.y += f2 * t * t;
            t = av.z + b2.z; acc.z += f2 * t * t;
            t = av.w + b2.w; acc.w += f2 * t * t;
            t = av.x + b3.x; acc.x += f3 * t * t;
            t = av.y + b3.y; acc.y += f3 * t * t;
            t = av.z + b3.z; acc.z += f3 * t * t;
            t = av.w + b3.w; acc.w += f3 * t * t;
        }
    }
    acc.x += __shfl_xor(acc.x, 16); acc.y += __shfl_xor(acc.y, 16);
    acc.z += __shfl_xor(acc.z, 16); acc.w += __shfl_xor(acc.w, 16);
    acc.x += __shfl_xor(acc.x, 32); acc.y += __shfl_xor(acc.y, 32);
    acc.z += __shfl_xor(acc.z, 32); acc.w += __shfl_xor(acc.w, 32);
    if (grp == 0) {
        int deg = s1 - s0;
        float inv = 1.f / (float)max(deg, 1);
        float4 r = make_float4(tanhf(acc.x * inv), tanhf(acc.y * inv),
                               tanhf(acc.z * inv), tanhf(acc.w * inv));
        ((float4*)out)[(size_t)node * 16 + col] = r;
    }
}

// ---------------------------------------------------------------------------
extern "C" void kernel_launch(void* const* d_in, const int* in_sizes, int n_in,
                              void* d_out, int out_size, void* d_ws, size_t ws_size,
                              hipStream_t stream) {
    const float* X      = (const float*)d_in[0];
    const int*   ei     = (const int*)d_in[1];
    const float* Wself  = (const float*)d_in[2];
    const float* Wneigh = (const float*)d_in[3];
    const float* bconv  = (const float*)d_in[4];
    const float* Qw     = (const float*)d_in[5];
    const float* Qb     = (const float*)d_in[6];

    int N = in_sizes[0] / NHID;
    int E = in_sizes[1] / 2;
    const int* src = ei;        // edge_index[0]
    const int* dst = ei + E;    // edge_index[1]
    int nB = (N + NPB - 1) >> NPB_SHIFT;           // 391 for N=100K
    int nChunks = (E + CHUNK - 1) / CHUNK;         // 391 for E=3.2M

    // ---- workspace layout (~103 MB) ----
    char* ws = (char*)d_ws;
    size_t bufBytes = (size_t)MAXB * CAP * 4;      // 21.0 MB per side
    unsigned int* buf0 = (unsigned int*)(ws);
    unsigned int* buf1 = (unsigned int*)(ws + bufBytes);
    float* aggF = (float*)(ws);                                   // after build
    float* aF   = (float*)(ws + (size_t)N * NHID * 4);
    float* bF   = (float*)(ws + (size_t)2 * N * NHID * 4);
    size_t pos = (size_t)3 * N * NHID * 4;
    if (pos < 2 * bufBytes) pos = 2 * bufBytes;
    pos = (pos + 255) & ~(size_t)255;
    auto alloc = [&](size_t bytes) -> void* {
        void* p = ws + pos;
        pos = (pos + bytes + 255) & ~(size_t)255;
        return p;
    };
    int* csr0   = (int*)alloc((size_t)E * 4);      // by dst
    int* csr1   = (int*)alloc((size_t)E * 4);      // by src
    int* off0   = (int*)alloc((size_t)(N + 1) * 4);
    int* off1   = (int*)alloc((size_t)(N + 1) * 4);
    int* btail0 = (int*)alloc((size_t)MAXB * 4);
    int* btail1 = (int*)alloc((size_t)MAXB * 4);
    int* boff0  = (int*)alloc((size_t)MAXB * 4);
    int* boff1  = (int*)alloc((size_t)MAXB * 4);
    float* W2   = (float*)alloc((size_t)8192 * 4); // repacked [A|B], 32KB
    (void)ws_size; (void)n_in; (void)out_size;

    hipMemsetAsync(btail0, 0, (size_t)2 * MAXB * 4, stream);   // btail0+btail1 contiguous

    k_bucketA<<<nChunks, 256, 0, stream>>>(src, dst, buf0, buf1, btail0, btail1, E, nB);
    k_bscan<<<1, 512, 0, stream>>>(btail0, btail1, boff0, boff1, off0, off1, nB, N);
    k_repackB<<<32, 256, 0, stream>>>(Qw, W2);
    k_bucket_csr<<<nB * 2, 256, 0, stream>>>(buf0, buf1, btail0, btail1,
                                             boff0, boff1, off0, off1, csr0, csr1, N);
    k_agg<<<(N + 3) / 4, 256, 0, stream>>>(X, off0, csr0, aggF, N);
    k_phaseA<<<(N + 63) / 64, 256, 0, stream>>>(X, aggF, Wself, Wneigh, bconv, aggF, N);
    k_phaseB<<<(N + 31) / 32, 256, 0, stream>>>(aggF, W2, Qb, aF, bF, N);
    k_final<<<(N + 3) / 4, 256, 0, stream>>>(aF, bF, off1, csr1, (float*)d_out, N);
}

// Round 8
// 362.875 us; speedup vs baseline: 2.5895x; 1.2464x over previous
//
#include <hip/hip_runtime.h>
#include <math.h>

#define NHID 64
#define NPB 256          // nodes per bucket (power of two; local id = node & 255)
#define NPB_SHIFT 8
#define MAXB 512         // supports N up to 131072
#define CAP 10240        // entries per bucket region (mean 8184 @ E=3.2M, +23 sigma)
#define CHUNK 8192       // edges per k_bucketA block

__device__ __forceinline__ float bf_lo(unsigned u) { return __uint_as_float(u << 16); }
__device__ __forceinline__ float bf_hi(unsigned u) { return __uint_as_float(u & 0xffff0000u); }
__device__ __forceinline__ unsigned f2bf(float f) {           // RNE bf16 (top 16 bits)
    unsigned u = __float_as_uint(f);
    return (u + 0x7fffu + ((u >> 16) & 1u)) >> 16;
}

// ---------------------------------------------------------------------------
// K_A: two-level bucketing of both endpoints (LDS histogram + slice reserve).
// ---------------------------------------------------------------------------
__global__ __launch_bounds__(256) void k_bucketA(const int* __restrict__ src,
                                                 const int* __restrict__ dst,
                                                 unsigned int* __restrict__ buf0,
                                                 unsigned int* __restrict__ buf1,
                                                 int* __restrict__ btail0,
                                                 int* __restrict__ btail1,
                                                 int E, int nB) {
    __shared__ int h0[MAXB], h1[MAXB], b0[MAXB], b1[MAXB];
    int tid = threadIdx.x;
    for (int i = tid; i < nB; i += 256) { h0[i] = 0; h1[i] = 0; }
    __syncthreads();
    int e0 = blockIdx.x * CHUNK;
    for (int i = tid; i < CHUNK; i += 256) {
        int e = e0 + i;
        if (e < E) {
            atomicAdd(&h0[dst[e] >> NPB_SHIFT], 1);
            atomicAdd(&h1[src[e] >> NPB_SHIFT], 1);
        }
    }
    __syncthreads();
    for (int i = tid; i < nB; i += 256) {
        int c0 = h0[i], c1 = h1[i];
        b0[i] = c0 ? atomicAdd(&btail0[i], c0) : 0;
        b1[i] = c1 ? atomicAdd(&btail1[i], c1) : 0;
        h0[i] = 0; h1[i] = 0;       // reuse as rank counters
    }
    __syncthreads();
    for (int i = tid; i < CHUNK; i += 256) {
        int e = e0 + i;
        if (e < E) {
            int d = dst[e], s = src[e];
            int bb = d >> NPB_SHIFT;
            int r = atomicAdd(&h0[bb], 1) + b0[bb];
            if (r < CAP)
                buf0[(size_t)bb * CAP + r] = ((unsigned)s << NPB_SHIFT) | (unsigned)(d & (NPB - 1));
            bb = s >> NPB_SHIFT;
            r = atomicAdd(&h1[bb], 1) + b1[bb];
            if (r < CAP)
                buf1[(size_t)bb * CAP + r] = ((unsigned)d << NPB_SHIFT) | (unsigned)(s & (NPB - 1));
        }
    }
}

// ---------------------------------------------------------------------------
// K_B: single-block exclusive scan of per-bucket sizes (both sides).
// ---------------------------------------------------------------------------
__global__ __launch_bounds__(512) void k_bscan(const int* __restrict__ btail0,
                                               const int* __restrict__ btail1,
                                               int* __restrict__ boff0, int* __restrict__ boff1,
                                               int* __restrict__ off0, int* __restrict__ off1,
                                               int nB, int N) {
    __shared__ int sd[512];
    int tid = threadIdx.x;
    int v = (tid < nB) ? min(btail0[tid], CAP) : 0;
    sd[tid] = v; __syncthreads();
    for (int o = 1; o < 512; o <<= 1) {
        int t = (tid >= o) ? sd[tid - o] : 0; __syncthreads();
        sd[tid] += t; __syncthreads();
    }
    if (tid < nB) boff0[tid] = sd[tid] - v;
    if (tid == 511) off0[N] = sd[511];
    __syncthreads();
    v = (tid < nB) ? min(btail1[tid], CAP) : 0;
    sd[tid] = v; __syncthreads();
    for (int o = 1; o < 512; o <<= 1) {
        int t = (tid >= o) ? sd[tid - o] : 0; __syncthreads();
        sd[tid] += t; __syncthreads();
    }
    if (tid < nB) boff1[tid] = sd[tid] - v;
    if (tid == 511) off1[N] = sd[511];
}

// ---------------------------------------------------------------------------
// K_C: per (side,bucket): LDS count -> LDS scan -> off[] -> ranked scatter.
// ---------------------------------------------------------------------------
__global__ __launch_bounds__(256) void k_bucket_csr(const unsigned int* __restrict__ buf0,
                                                    const unsigned int* __restrict__ buf1,
                                                    const int* __restrict__ btail0,
                                                    const int* __restrict__ btail1,
                                                    const int* __restrict__ boff0,
                                                    const int* __restrict__ boff1,
                                                    int* __restrict__ off0, int* __restrict__ off1,
                                                    int* __restrict__ csr0, int* __restrict__ csr1,
                                                    int N) {
    int side = blockIdx.x & 1;
    int b = blockIdx.x >> 1;
    const unsigned int* buf = (side ? buf1 : buf0) + (size_t)b * CAP;
    int cnt_b = min((side ? btail1 : btail0)[b], CAP);
    int boff  = (side ? boff1 : boff0)[b];
    int* off  = side ? off1 : off0;
    int* csr  = side ? csr1 : csr0;
    __shared__ int cnt[NPB];
    __shared__ int scn[NPB];
    __shared__ int cur[NPB];
    int tid = threadIdx.x;          // blockDim == NPB == 256
    cnt[tid] = 0;
    __syncthreads();
    for (int i = tid; i < cnt_b; i += 256)
        atomicAdd(&cnt[buf[i] & (NPB - 1)], 1);
    __syncthreads();
    int v = cnt[tid];
    scn[tid] = v; __syncthreads();
    for (int o = 1; o < 256; o <<= 1) {
        int t = (tid >= o) ? scn[tid - o] : 0; __syncthreads();
        scn[tid] += t; __syncthreads();
    }
    int base = boff + scn[tid] - v;   // exclusive
    cur[tid] = base;
    int node = (b << NPB_SHIFT) + tid;
    if (node < N) off[node] = base;
    __syncthreads();
    for (int i = tid; i < cnt_b; i += 256) {
        unsigned int u = buf[i];
        int pos = atomicAdd(&cur[u & (NPB - 1)], 1);
        csr[pos] = (int)(u >> NPB_SHIFT);
    }
}

// ---------------------------------------------------------------------------
// K_X: pack X (f32) -> Xb (bf16, RNE). 8 values per thread.
// ---------------------------------------------------------------------------
__global__ __launch_bounds__(256) void k_xcast(const float* __restrict__ X,
                                               unsigned* __restrict__ Xb, int total8) {
    int i = blockIdx.x * 256 + threadIdx.x;
    if (i >= total8) return;
    const float4* Xv = (const float4*)X;
    float4 f0 = Xv[(size_t)i * 2];
    float4 f1 = Xv[(size_t)i * 2 + 1];
    uint4 p;
    p.x = f2bf(f0.x) | (f2bf(f0.y) << 16);
    p.y = f2bf(f0.z) | (f2bf(f0.w) << 16);
    p.z = f2bf(f1.x) | (f2bf(f1.y) << 16);
    p.w = f2bf(f1.z) | (f2bf(f1.w) << 16);
    ((uint4*)Xb)[i] = p;
}

// ---------------------------------------------------------------------------
// K4: agg[n,:] = mean over in-edges of Xb[src,:] (bf16 rows, 128B = 1 line).
// Wave = 8 edge-groups x 8 lanes; one dwordx4 load covers 8 edges' rows;
// 2 loads (16 edges) in flight. Full iterations are mask-free.
// ---------------------------------------------------------------------------
__global__ __launch_bounds__(256) void k_agg(const unsigned* __restrict__ Xb,
                                             const int* __restrict__ off_dst,
                                             const int* __restrict__ csr_dst,
                                             float* __restrict__ agg, int N) {
    int lane = threadIdx.x & 63;
    int node = blockIdx.x * 4 + (threadIdx.x >> 6);
    if (node >= N) return;
    int grp = lane >> 3, col8 = lane & 7;
    const uint4* Xb4 = (const uint4*)Xb;          // row n -> Xb4[n*8 + col8]
    int s0 = off_dst[node], s1 = off_dst[node + 1];
    float4 accA = make_float4(0.f, 0.f, 0.f, 0.f);
    float4 accB = make_float4(0.f, 0.f, 0.f, 0.f);
    for (int base = s0; base < s1; base += 64) {
        int cnt = min(64, s1 - base);
        int idx = (base + lane < s1) ? csr_dst[base + lane] : 0;
        int jfull = cnt & ~15;
        for (int j = 0; j < jfull; j += 16) {
            int m0 = __shfl(idx, j + grp);
            int m1 = __shfl(idx, j + 8 + grp);
            uint4 u0 = Xb4[(size_t)m0 * 8 + col8];
            uint4 u1 = Xb4[(size_t)m1 * 8 + col8];
            accA.x += bf_lo(u0.x); accA.y += bf_hi(u0.x);
            accA.z += bf_lo(u0.y); accA.w += bf_hi(u0.y);
            accB.x += bf_lo(u0.z); accB.y += bf_hi(u0.z);
            accB.z += bf_lo(u0.w); accB.w += bf_hi(u0.w);
            accA.x += bf_lo(u1.x); accA.y += bf_hi(u1.x);
            accA.z += bf_lo(u1.y); accA.w += bf_hi(u1.y);
            accB.x += bf_lo(u1.z); accB.y += bf_hi(u1.z);
            accB.z += bf_lo(u1.w); accB.w += bf_hi(u1.w);
        }
        if (jfull < cnt) {
            int q0 = jfull + grp, q1 = jfull + 8 + grp;
            int m0 = __shfl(idx, q0);
            int m1 = __shfl(idx, q1);
            float f0 = (q0 < cnt) ? 1.f : 0.f; if (q0 >= cnt) m0 = 0;
            float f1 = (q1 < cnt) ? 1.f : 0.f; if (q1 >= cnt) m1 = 0;
            uint4 u0 = Xb4[(size_t)m0 * 8 + col8];
            uint4 u1 = Xb4[(size_t)m1 * 8 + col8];
            accA.x += f0 * bf_lo(u0.x); accA.y += f0 * bf_hi(u0.x);
            accA.z += f0 * bf_lo(u0.y); accA.w += f0 * bf_hi(u0.y);
            accB.x += f0 * bf_lo(u0.z); accB.y += f0 * bf_hi(u0.z);
            accB.z += f0 * bf_lo(u0.w); accB.w += f0 * bf_hi(u0.w);
            accA.x += f1 * bf_lo(u1.x); accA.y += f1 * bf_hi(u1.x);
            accA.z += f1 * bf_lo(u1.y); accA.w += f1 * bf_hi(u1.y);
            accB.x += f1 * bf_lo(u1.z); accB.y += f1 * bf_hi(u1.z);
            accB.z += f1 * bf_lo(u1.w); accB.w += f1 * bf_hi(u1.w);
        }
    }
    #pragma unroll
    for (int d = 8; d < 64; d <<= 1) {
        accA.x += __shfl_xor(accA.x, d); accA.y += __shfl_xor(accA.y, d);
        accA.z += __shfl_xor(accA.z, d); accA.w += __shfl_xor(accA.w, d);
        accB.x += __shfl_xor(accB.x, d); accB.y += __shfl_xor(accB.y, d);
        accB.z += __shfl_xor(accB.z, d); accB.w += __shfl_xor(accB.w, d);
    }
    if (grp == 0) {
        int deg = s1 - s0;
        float inv = 1.f / (float)max(deg, 1);
        float4 r0 = make_float4(accA.x * inv, accA.y * inv, accA.z * inv, accA.w * inv);
        float4 r1 = make_float4(accB.x * inv, accB.y * inv, accB.z * inv, accB.w * inv);
        ((float4*)agg)[(size_t)node * 16 + col8 * 2]     = r0;
        ((float4*)agg)[(size_t)node * 16 + col8 * 2 + 1] = r1;
    }
}

// ---------------------------------------------------------------------------
// K5a: X2 = relu(X·Wself + agg·Wneigh + b). Weights in LDS; 4 threads/node.
// In-place X2-over-agg safe (node's 4 threads share one wave).
// ---------------------------------------------------------------------------
__global__ __launch_bounds__(256) void k_phaseA(const float* __restrict__ X,
                                                const float* agg,
                                                const float* __restrict__ Ws,
                                                const float* __restrict__ Wn,
                                                const float* __restrict__ bconv,
                                                float* X2, int N) {
    __shared__ float sWs[4096];
    __shared__ float sWn[4096];
    __shared__ float sb[64];
    int tid = threadIdx.x;
    for (int i = tid; i < 4096; i += 256) {
        sWs[i] = Ws[i];
        sWn[i] = Wn[i];
    }
    if (tid < 64) sb[tid] = bconv[tid];
    __syncthreads();

    int n = blockIdx.x * 64 + (tid >> 2);
    if (n >= N) return;
    int wb = (tid & 3) << 2;
    const float4* ws4 = (const float4*)sWs;
    const float4* wn4 = (const float4*)sWn;
    const float4* bv  = (const float4*)sb;
    const float4* Xv  = (const float4*)(X + (size_t)n * NHID);
    const float4* Gv  = (const float4*)(agg + (size_t)n * NHID);
    float4 a0 = bv[wb], a1 = bv[wb + 1], a2 = bv[wb + 2], a3 = bv[wb + 3];
    #pragma unroll 2
    for (int q = 0; q < 16; ++q) {
        float4 xq = Xv[q];
        float4 gq = Gv[q];
        float xs[4] = {xq.x, xq.y, xq.z, xq.w};
        float gs[4] = {gq.x, gq.y, gq.z, gq.w};
        #pragma unroll
        for (int j = 0; j < 4; ++j) {
            int k16 = (4 * q + j) * 16 + wb;
            float4 w0 = ws4[k16], w1 = ws4[k16 + 1], w2 = ws4[k16 + 2], w3 = ws4[k16 + 3];
            float4 m0 = wn4[k16], m1 = wn4[k16 + 1], m2 = wn4[k16 + 2], m3 = wn4[k16 + 3];
            float xj = xs[j], gj = gs[j];
            a0.x += xj * w0.x + gj * m0.x; a0.y += xj * w0.y + gj * m0.y;
            a0.z += xj * w0.z + gj * m0.z; a0.w += xj * w0.w + gj * m0.w;
            a1.x += xj * w1.x + gj * m1.x; a1.y += xj * w1.y + gj * m1.y;
            a1.z += xj * w1.z + gj * m1.z; a1.w += xj * w1.w + gj * m1.w;
            a2.x += xj * w2.x + gj * m2.x; a2.y += xj * w2.y + gj * m2.y;
            a2.z += xj * w2.z + gj * m2.z; a2.w += xj * w2.w + gj * m2.w;
            a3.x += xj * w3.x + gj * m3.x; a3.y += xj * w3.y + gj * m3.y;
            a3.z += xj * w3.z + gj * m3.z; a3.w += xj * w3.w + gj * m3.w;
        }
    }
    float4* out = (float4*)(X2 + (size_t)n * NHID);
    out[wb]     = make_float4(fmaxf(a0.x, 0.f), fmaxf(a0.y, 0.f), fmaxf(a0.z, 0.f), fmaxf(a0.w, 0.f));
    out[wb + 1] = make_float4(fmaxf(a1.x, 0.f), fmaxf(a1.y, 0.f), fmaxf(a1.z, 0.f), fmaxf(a1.w, 0.f));
    out[wb + 2] = make_float4(fmaxf(a2.x, 0.f), fmaxf(a2.y, 0.f), fmaxf(a2.z, 0.f), fmaxf(a2.w, 0.f));
    out[wb + 3] = make_float4(fmaxf(a3.x, 0.f), fmaxf(a3.y, 0.f), fmaxf(a3.z, 0.f), fmaxf(a3.w, 0.f));
}

// ---------------------------------------------------------------------------
// K_rp: one-shot repack of Qw into W2[64][128] = [A|B] row-major.
// ---------------------------------------------------------------------------
__global__ __launch_bounds__(256) void k_repackB(const float* __restrict__ Qw,
                                                 float* __restrict__ W2) {
    int i = blockIdx.x * 256 + threadIdx.x;   // grid covers 8192
    if (i >= 8192) return;
    int f = i >> 7, c = i & 127;
    float v;
    if (c < 64) v = Qw[(c >> 4) * 2048 + f * 16 + (c & 15)];
    else { int cc = c - 64; v = Qw[(cc >> 4) * 2048 + (64 + f) * 16 + (cc & 15)]; }
    W2[i] = v;
}

// ---------------------------------------------------------------------------
// K5b: [a|b] = X2 · W2 (+[Qb|0]). W2 in LDS. 8 threads/node.
// a written f32; b written PACKED BF16 (gather side of k_final).
// ---------------------------------------------------------------------------
__global__ __launch_bounds__(256) void k_phaseB(const float* __restrict__ X2,
                                                const float* __restrict__ W2,
                                                const float* __restrict__ Qb,
                                                float* __restrict__ aOut,
                                                unsigned* __restrict__ bOut, int N) {
    __shared__ float sW[8192];
    int tid = threadIdx.x;
    for (int i = tid; i < 8192; i += 256) sW[i] = W2[i];
    __syncthreads();

    int n = blockIdx.x * 32 + (tid >> 3);
    if (n >= N) return;
    int part = tid & 7;                 // 0..3 -> a cols, 4..7 -> b cols
    int wb = part << 2;                 // float4 base within 32-float4 row
    const float4* w4 = (const float4*)sW;
    float4 a0, a1, a2, a3;
    if (part < 4) {
        const float4* qv = (const float4*)Qb;
        a0 = qv[wb]; a1 = qv[wb + 1]; a2 = qv[wb + 2]; a3 = qv[wb + 3];
    } else {
        a0 = a1 = a2 = a3 = make_float4(0.f, 0.f, 0.f, 0.f);
    }
    const float4* Xv = (const float4*)(X2 + (size_t)n * NHID);
    #pragma unroll 2
    for (int q = 0; q < 16; ++q) {
        float4 xq = Xv[q];
        float xs[4] = {xq.x, xq.y, xq.z, xq.w};
        #pragma unroll
        for (int j = 0; j < 4; ++j) {
            int f32b = (4 * q + j) * 32 + wb;
            float4 w0 = w4[f32b], w1 = w4[f32b + 1], w2 = w4[f32b + 2], w3 = w4[f32b + 3];
            float xj = xs[j];
            a0.x += xj * w0.x; a0.y += xj * w0.y; a0.z += xj * w0.z; a0.w += xj * w0.w;
            a1.x += xj * w1.x; a1.y += xj * w1.y; a1.z += xj * w1.z; a1.w += xj * w1.w;
            a2.x += xj * w2.x; a2.y += xj * w2.y; a2.z += xj * w2.z; a2.w += xj * w2.w;
            a3.x += xj * w3.x; a3.y += xj * w3.y; a3.z += xj * w3.z; a3.w += xj * w3.w;
        }
    }
    if (part < 4) {
        float4* outp = (float4*)(aOut + (size_t)n * NHID) + wb;
        outp[0] = a0; outp[1] = a1; outp[2] = a2; outp[3] = a3;
    } else {
        uint4 p0, p1;
        p0.x = f2bf(a0.x) | (f2bf(a0.y) << 16);
        p0.y = f2bf(a0.z) | (f2bf(a0.w) << 16);
        p0.z = f2bf(a1.x) | (f2bf(a1.y) << 16);
        p0.w = f2bf(a1.z) | (f2bf(a1.w) << 16);
        p1.x = f2bf(a2.x) | (f2bf(a2.y) << 16);
        p1.y = f2bf(a2.z) | (f2bf(a2.w) << 16);
        p1.z = f2bf(a3.x) | (f2bf(a3.y) << 16);
        p1.w = f2bf(a3.z) | (f2bf(a3.w) << 16);
        uint4* outp = (uint4*)bOut + (size_t)n * 8 + (part - 4) * 2;
        outp[0] = p0; outp[1] = p1;
    }
}

// ---------------------------------------------------------------------------
// K6: gg[n,:] = tanh(mean over out-edges of (a[n,:] + b[dst,:])^2)
// b rows are bf16 (128B = 1 line); same 8x8 structure as K4.
// ---------------------------------------------------------------------------
__global__ __launch_bounds__(256) void k_final(const float* __restrict__ aF,
                                               const unsigned* __restrict__ bFb,
                                               const int* __restrict__ off_src,
                                               const int* __restrict__ csr_src,
                                               float* __restrict__ out, int N) {
    int lane = threadIdx.x & 63;
    int node = blockIdx.x * 4 + (threadIdx.x >> 6);
    if (node >= N) return;
    int grp = lane >> 3, col8 = lane & 7;
    const uint4* Bv = (const uint4*)bFb;
    const float4* Av = (const float4*)aF;
    float4 avA = Av[(size_t)node * 16 + col8 * 2];
    float4 avB = Av[(size_t)node * 16 + col8 * 2 + 1];
    int s0 = off_src[node], s1 = off_src[node + 1];
    float4 accA = make_float4(0.f, 0.f, 0.f, 0.f);
    float4 accB = make_float4(0.f, 0.f, 0.f, 0.f);
    for (int base = s0; base < s1; base += 64) {
        int cnt = min(64, s1 - base);
        int idx = (base + lane < s1) ? csr_src[base + lane] : 0;
        int jfull = cnt & ~15;
        for (int j = 0; j < jfull; j += 16) {
            int m0 = __shfl(idx, j + grp);
            int m1 = __shfl(idx, j + 8 + grp);
            uint4 u0 = Bv[(size_t)m0 * 8 + col8];
            uint4 u1 = Bv[(size_t)m1 * 8 + col8];
            float t;
            t = avA.x + bf_lo(u0.x); accA.x += t * t;
            t = avA.y + bf_hi(u0.x); accA.y += t * t;
            t = avA.z + bf_lo(u0.y); accA.z += t * t;
            t = avA.w + bf_hi(u0.y); accA.w += t * t;
            t = avB.x + bf_lo(u0.z); accB.x += t * t;
            t = avB.y + bf_hi(u0.z); accB.y += t * t;
            t = avB.z + bf_lo(u0.w); accB.z += t * t;
            t = avB.w + bf_hi(u0.w); accB.w += t * t;
            t = avA.x + bf_lo(u1.x); accA.x += t * t;
            t = avA.y + bf_hi(u1.x); accA.y += t * t;
            t = avA.z + bf_lo(u1.y); accA.z += t * t;
            t = avA.w + bf_hi(u1.y); accA.w += t * t;
            t = avB.x + bf_lo(u1.z); accB.x += t * t;
            t = avB.y + bf_hi(u1.z); accB.y += t * t;
            t = avB.z + bf_lo(u1.w); accB.z += t * t;
            t = avB.w + bf_hi(u1.w); accB.w += t * t;
        }
        if (jfull < cnt) {
            int q0 = jfull + grp, q1 = jfull + 8 + grp;
            int m0 = __shfl(idx, q0);
            int m1 = __shfl(idx, q1);
            float f0 = (q0 < cnt) ? 1.f : 0.f; if (q0 >= cnt) m0 = 0;
            float f1 = (q1 < cnt) ? 1.f : 0.f; if (q1 >= cnt) m1 = 0;
            uint4 u0 = Bv[(size_t)m0 * 8 + col8];
            uint4 u1 = Bv[(size_t)m1 * 8 + col8];
            float t;
            t = avA.x + bf_lo(u0.x); accA.x += f0 * t * t;
            t = avA.y + bf_hi(u0.x); accA.y += f0 * t * t;
            t = avA.z + bf_lo(u0.y); accA.z += f0 * t * t;
            t = avA.w + bf_hi(u0.y); accA.w += f0 * t * t;
            t = avB.x + bf_lo(u0.z); accB.x += f0 * t * t;
            t = avB.y + bf_hi(u0.z); accB.y += f0 * t * t;
            t = avB.z + bf_lo(u0.w); accB.z += f0 * t * t;
            t = avB.w + bf_hi(u0.w); accB.w += f0 * t * t;
            t = avA.x + bf_lo(u1.x); accA.x += f1 * t * t;
            t = avA.y + bf_hi(u1.x); accA.y += f1 * t * t;
            t = avA.z + bf_lo(u1.y); accA.z += f1 * t * t;
            t = avA.w + bf_hi(u1.y); accA.w += f1 * t * t;
            t = avB.x + bf_lo(u1.z); accB.x += f1 * t * t;
            t = avB.y + bf_hi(u1.z); accB.y += f1 * t * t;
            t = avB.z + bf_lo(u1.w); accB.z += f1 * t * t;
            t = avB.w + bf_hi(u1.w); accB.w += f1 * t * t;
        }
    }
    #pragma unroll
    for (int d = 8; d < 64; d <<= 1) {
        accA.x += __shfl_xor(accA.x, d); accA.y += __shfl_xor(accA.y, d);
        accA.z += __shfl_xor(accA.z, d); accA.w += __shfl_xor(accA.w, d);
        accB.x += __shfl_xor(accB.x, d); accB.y += __shfl_xor(accB.y, d);
        accB.z += __shfl_xor(accB.z, d); accB.w += __shfl_xor(accB.w, d);
    }
    if (grp == 0) {
        int deg = s1 - s0;
        float inv = 1.f / (float)max(deg, 1);
        float4 r0 = make_float4(tanhf(accA.x * inv), tanhf(accA.y * inv),
                                tanhf(accA.z * inv), tanhf(accA.w * inv));
        float4 r1 = make_float4(tanhf(accB.x * inv), tanhf(accB.y * inv),
                                tanhf(accB.z * inv), tanhf(accB.w * inv));
        ((float4*)out)[(size_t)node * 16 + col8 * 2]     = r0;
        ((float4*)out)[(size_t)node * 16 + col8 * 2 + 1] = r1;
    }
}

// ---------------------------------------------------------------------------
extern "C" void kernel_launch(void* const* d_in, const int* in_sizes, int n_in,
                              void* d_out, int out_size, void* d_ws, size_t ws_size,
                              hipStream_t stream) {
    const float* X      = (const float*)d_in[0];
    const int*   ei     = (const int*)d_in[1];
    const float* Wself  = (const float*)d_in[2];
    const float* Wneigh = (const float*)d_in[3];
    const float* bconv  = (const float*)d_in[4];
    const float* Qw     = (const float*)d_in[5];
    const float* Qb     = (const float*)d_in[6];

    int N = in_sizes[0] / NHID;
    int E = in_sizes[1] / 2;
    const int* src = ei;        // edge_index[0]
    const int* dst = ei + E;    // edge_index[1]
    int nB = (N + NPB - 1) >> NPB_SHIFT;           // 391 for N=100K
    int nChunks = (E + CHUNK - 1) / CHUNK;         // 391 for E=3.2M

    // ---- workspace layout (~103 MB) ----
    char* ws = (char*)d_ws;
    size_t bufBytes = (size_t)MAXB * CAP * 4;      // 21.0 MB per side
    size_t NH4 = (size_t)N * NHID * 4;             // 25.6 MB
    size_t NH2 = (size_t)N * NHID * 2;             // 12.8 MB
    unsigned int* buf0 = (unsigned int*)(ws);
    unsigned int* buf1 = (unsigned int*)(ws + bufBytes);
    float*    aggF = (float*)(ws);                              // after build
    float*    aF   = (float*)(ws + NH4);
    unsigned* bFb  = (unsigned*)(ws + 2 * NH4);                 // bf16 rows
    unsigned* Xb   = (unsigned*)(ws + 2 * NH4 + NH2);           // bf16 rows
    size_t pos = 3 * NH4;                                       // 76.8 MB
    if (pos < 2 * bufBytes) pos = 2 * bufBytes;
    pos = (pos + 255) & ~(size_t)255;
    auto alloc = [&](size_t bytes) -> void* {
        void* p = ws + pos;
        pos = (pos + bytes + 255) & ~(size_t)255;
        return p;
    };
    int* csr0   = (int*)alloc((size_t)E * 4);      // by dst
    int* csr1   = (int*)alloc((size_t)E * 4);      // by src
    int* off0   = (int*)alloc((size_t)(N + 1) * 4);
    int* off1   = (int*)alloc((size_t)(N + 1) * 4);
    int* btail0 = (int*)alloc((size_t)MAXB * 4);
    int* btail1 = (int*)alloc((size_t)MAXB * 4);
    int* boff0  = (int*)alloc((size_t)MAXB * 4);
    int* boff1  = (int*)alloc((size_t)MAXB * 4);
    float* W2   = (float*)alloc((size_t)8192 * 4); // repacked [A|B], 32KB
    (void)ws_size; (void)n_in; (void)out_size;

    hipMemsetAsync(btail0, 0, (size_t)2 * MAXB * 4, stream);   // btail0+btail1 contiguous

    k_bucketA<<<nChunks, 256, 0, stream>>>(src, dst, buf0, buf1, btail0, btail1, E, nB);
    k_bscan<<<1, 512, 0, stream>>>(btail0, btail1, boff0, boff1, off0, off1, nB, N);
    k_repackB<<<32, 256, 0, stream>>>(Qw, W2);
    k_xcast<<<(N * 8 + 255) / 256, 256, 0, stream>>>(X, Xb, N * 8);
    k_bucket_csr<<<nB * 2, 256, 0, stream>>>(buf0, buf1, btail0, btail1,
                                             boff0, boff1, off0, off1, csr0, csr1, N);
    k_agg<<<(N + 3) / 4, 256, 0, stream>>>(Xb, off0, csr0, aggF, N);
    k_phaseA<<<(N + 63) / 64, 256, 0, stream>>>(X, aggF, Wself, Wneigh, bconv, aggF, N);
    k_phaseB<<<(N + 31) / 32, 256, 0, stream>>>(aggF, W2, Qb, aF, bFb, N);
    k_final<<<(N + 3) / 4, 256, 0, stream>>>(aF, bFb, off1, csr1, (float*)d_out, N);
}

// Round 9
// 329.619 us; speedup vs baseline: 2.8508x; 1.1009x over previous
//
#include <hip/hip_runtime.h>
#include <math.h>

#define NHID 64
#define NPB 512          // nodes per bucket (power of two; local id = node & 511)
#define NPB_SHIFT 9
#define MAXB 256         // supports N up to 131072
#define CAP 20480        // entries per bucket region (mean 16384 @ E=3.2M, +32 sigma)
#define CHUNK 8192       // edges per k_bucketA block

__device__ __forceinline__ float bf_lo(unsigned u) { return __uint_as_float(u << 16); }
__device__ __forceinline__ float bf_hi(unsigned u) { return __uint_as_float(u & 0xffff0000u); }
__device__ __forceinline__ unsigned f2bf(float f) {           // RNE bf16 (top 16 bits)
    unsigned u = __float_as_uint(f);
    return (u + 0x7fffu + ((u >> 16) & 1u)) >> 16;
}

// ---------------------------------------------------------------------------
// K_A: bucketing, ONE (chunk,side) PER BLOCK (side-split for occupancy +
// smaller hot tail set). LDS histogram over <=256 coarse buckets -> one
// global atomic per (block,bucket) reserves a slice (~42 entries = 168B ->
// ~2x write amp instead of 5x) -> rank-scatter of packed (payload<<9|local).
// ---------------------------------------------------------------------------
__global__ __launch_bounds__(256) void k_bucketA(const int* __restrict__ src,
                                                 const int* __restrict__ dst,
                                                 unsigned int* __restrict__ buf0,  // keyed by dst, payload src
                                                 unsigned int* __restrict__ buf1,  // keyed by src, payload dst
                                                 int* __restrict__ btail0,
                                                 int* __restrict__ btail1,
                                                 int E, int nB, int nChunks) {
    int side  = blockIdx.x & 1;
    int chunk = blockIdx.x >> 1;
    const int* key = side ? src : dst;
    const int* pay = side ? dst : src;
    unsigned int* buf = side ? buf1 : buf0;
    int* btail = side ? btail1 : btail0;

    __shared__ int h[MAXB], b[MAXB];
    int tid = threadIdx.x;
    for (int i = tid; i < nB; i += 256) h[i] = 0;
    __syncthreads();
    int e0 = chunk * CHUNK;
    // pass 1: histogram (int4 reads)
    for (int i = tid; i < CHUNK / 4; i += 256) {
        int e = e0 + i * 4;
        if (e + 3 < E) {
            int4 k4 = ((const int4*)(key + e0))[i];
            atomicAdd(&h[k4.x >> NPB_SHIFT], 1);
            atomicAdd(&h[k4.y >> NPB_SHIFT], 1);
            atomicAdd(&h[k4.z >> NPB_SHIFT], 1);
            atomicAdd(&h[k4.w >> NPB_SHIFT], 1);
        } else {
            for (int j = 0; j < 4; ++j) {
                int e2 = e + j;
                if (e2 < E) atomicAdd(&h[key[e2] >> NPB_SHIFT], 1);
            }
        }
    }
    __syncthreads();
    // reserve slices
    for (int i = tid; i < nB; i += 256) {
        int c = h[i];
        b[i] = c ? atomicAdd(&btail[i], c) : 0;
        h[i] = 0;                    // reuse as rank counter
    }
    __syncthreads();
    // pass 2: scatter
    for (int i = tid; i < CHUNK / 4; i += 256) {
        int e = e0 + i * 4;
        if (e + 3 < E) {
            int4 k4 = ((const int4*)(key + e0))[i];
            int4 p4 = ((const int4*)(pay + e0))[i];
            int bb, r;
            bb = k4.x >> NPB_SHIFT; r = atomicAdd(&h[bb], 1) + b[bb];
            if (r < CAP) buf[(size_t)bb * CAP + r] = ((unsigned)p4.x << NPB_SHIFT) | (unsigned)(k4.x & (NPB - 1));
            bb = k4.y >> NPB_SHIFT; r = atomicAdd(&h[bb], 1) + b[bb];
            if (r < CAP) buf[(size_t)bb * CAP + r] = ((unsigned)p4.y << NPB_SHIFT) | (unsigned)(k4.y & (NPB - 1));
            bb = k4.z >> NPB_SHIFT; r = atomicAdd(&h[bb], 1) + b[bb];
            if (r < CAP) buf[(size_t)bb * CAP + r] = ((unsigned)p4.z << NPB_SHIFT) | (unsigned)(k4.z & (NPB - 1));
            bb = k4.w >> NPB_SHIFT; r = atomicAdd(&h[bb], 1) + b[bb];
            if (r < CAP) buf[(size_t)bb * CAP + r] = ((unsigned)p4.w << NPB_SHIFT) | (unsigned)(k4.w & (NPB - 1));
        } else {
            for (int j = 0; j < 4; ++j) {
                int e2 = e + j;
                if (e2 < E) {
                    int k = key[e2], p = pay[e2];
                    int bb = k >> NPB_SHIFT;
                    int r = atomicAdd(&h[bb], 1) + b[bb];
                    if (r < CAP) buf[(size_t)bb * CAP + r] = ((unsigned)p << NPB_SHIFT) | (unsigned)(k & (NPB - 1));
                }
            }
        }
    }
}

// ---------------------------------------------------------------------------
// K_B: single-block exclusive scan of per-bucket sizes (both sides).
// nB <= 256.
// ---------------------------------------------------------------------------
__global__ __launch_bounds__(256) void k_bscan(const int* __restrict__ btail0,
                                               const int* __restrict__ btail1,
                                               int* __restrict__ boff0, int* __restrict__ boff1,
                                               int* __restrict__ off0, int* __restrict__ off1,
                                               int nB, int N) {
    __shared__ int sd[256];
    int tid = threadIdx.x;
    int v = (tid < nB) ? min(btail0[tid], CAP) : 0;
    sd[tid] = v; __syncthreads();
    for (int o = 1; o < 256; o <<= 1) {
        int t = (tid >= o) ? sd[tid - o] : 0; __syncthreads();
        sd[tid] += t; __syncthreads();
    }
    if (tid < nB) boff0[tid] = sd[tid] - v;
    if (tid == 255) off0[N] = sd[255];
    __syncthreads();
    v = (tid < nB) ? min(btail1[tid], CAP) : 0;
    sd[tid] = v; __syncthreads();
    for (int o = 1; o < 256; o <<= 1) {
        int t = (tid >= o) ? sd[tid - o] : 0; __syncthreads();
        sd[tid] += t; __syncthreads();
    }
    if (tid < nB) boff1[tid] = sd[tid] - v;
    if (tid == 255) off1[N] = sd[255];
}

// ---------------------------------------------------------------------------
// K_C: per (side,bucket), 512 threads: LDS count -> LDS scan -> off[] ->
// ranked scatter into the bucket's csr window. Zero global atomics.
// ---------------------------------------------------------------------------
__global__ __launch_bounds__(512) void k_bucket_csr(const unsigned int* __restrict__ buf0,
                                                    const unsigned int* __restrict__ buf1,
                                                    const int* __restrict__ btail0,
                                                    const int* __restrict__ btail1,
                                                    const int* __restrict__ boff0,
                                                    const int* __restrict__ boff1,
                                                    int* __restrict__ off0, int* __restrict__ off1,
                                                    int* __restrict__ csr0, int* __restrict__ csr1,
                                                    int N) {
    int side = blockIdx.x & 1;
    int b = blockIdx.x >> 1;
    const unsigned int* buf = (side ? buf1 : buf0) + (size_t)b * CAP;
    int cnt_b = min((side ? btail1 : btail0)[b], CAP);
    int boff  = (side ? boff1 : boff0)[b];
    int* off  = side ? off1 : off0;
    int* csr  = side ? csr1 : csr0;
    __shared__ int cnt[NPB];
    __shared__ int scn[NPB];
    __shared__ int cur[NPB];
    int tid = threadIdx.x;          // blockDim == NPB == 512
    cnt[tid] = 0;
    __syncthreads();
    for (int i = tid; i < cnt_b; i += 512)
        atomicAdd(&cnt[buf[i] & (NPB - 1)], 1);
    __syncthreads();
    int v = cnt[tid];
    scn[tid] = v; __syncthreads();
    for (int o = 1; o < 512; o <<= 1) {
        int t = (tid >= o) ? scn[tid - o] : 0; __syncthreads();
        scn[tid] += t; __syncthreads();
    }
    int base = boff + scn[tid] - v;   // exclusive
    cur[tid] = base;
    int node = (b << NPB_SHIFT) + tid;
    if (node < N) off[node] = base;
    __syncthreads();
    for (int i = tid; i < cnt_b; i += 512) {
        unsigned int u = buf[i];
        int pos = atomicAdd(&cur[u & (NPB - 1)], 1);
        csr[pos] = (int)(u >> NPB_SHIFT);
    }
}

// ---------------------------------------------------------------------------
// K_X: pack X (f32) -> Xb (bf16, RNE). 8 values per thread.
// ---------------------------------------------------------------------------
__global__ __launch_bounds__(256) void k_xcast(const float* __restrict__ X,
                                               unsigned* __restrict__ Xb, int total8) {
    int i = blockIdx.x * 256 + threadIdx.x;
    if (i >= total8) return;
    const float4* Xv = (const float4*)X;
    float4 f0 = Xv[(size_t)i * 2];
    float4 f1 = Xv[(size_t)i * 2 + 1];
    uint4 p;
    p.x = f2bf(f0.x) | (f2bf(f0.y) << 16);
    p.y = f2bf(f0.z) | (f2bf(f0.w) << 16);
    p.z = f2bf(f1.x) | (f2bf(f1.y) << 16);
    p.w = f2bf(f1.z) | (f2bf(f1.w) << 16);
    ((uint4*)Xb)[i] = p;
}

// ---------------------------------------------------------------------------
// K4: agg[n,:] = mean over in-edges of Xb[src,:] (bf16 rows, 128B = 1 line).
// Wave = 8 edge-groups x 8 lanes; one dwordx4 load covers 8 edges' rows;
// 2 loads (16 edges) in flight. Full iterations are mask-free.
// ---------------------------------------------------------------------------
__global__ __launch_bounds__(256) void k_agg(const unsigned* __restrict__ Xb,
                                             const int* __restrict__ off_dst,
                                             const int* __restrict__ csr_dst,
                                             float* __restrict__ agg, int N) {
    int lane = threadIdx.x & 63;
    int node = blockIdx.x * 4 + (threadIdx.x >> 6);
    if (node >= N) return;
    int grp = lane >> 3, col8 = lane & 7;
    const uint4* Xb4 = (const uint4*)Xb;          // row n -> Xb4[n*8 + col8]
    int s0 = off_dst[node], s1 = off_dst[node + 1];
    float4 accA = make_float4(0.f, 0.f, 0.f, 0.f);
    float4 accB = make_float4(0.f, 0.f, 0.f, 0.f);
    for (int base = s0; base < s1; base += 64) {
        int cnt = min(64, s1 - base);
        int idx = (base + lane < s1) ? csr_dst[base + lane] : 0;
        int jfull = cnt & ~15;
        for (int j = 0; j < jfull; j += 16) {
            int m0 = __shfl(idx, j + grp);
            int m1 = __shfl(idx, j + 8 + grp);
            uint4 u0 = Xb4[(size_t)m0 * 8 + col8];
            uint4 u1 = Xb4[(size_t)m1 * 8 + col8];
            accA.x += bf_lo(u0.x); accA.y += bf_hi(u0.x);
            accA.z += bf_lo(u0.y); accA.w += bf_hi(u0.y);
            accB.x += bf_lo(u0.z); accB.y += bf_hi(u0.z);
            accB.z += bf_lo(u0.w); accB.w += bf_hi(u0.w);
            accA.x += bf_lo(u1.x); accA.y += bf_hi(u1.x);
            accA.z += bf_lo(u1.y); accA.w += bf_hi(u1.y);
            accB.x += bf_lo(u1.z); accB.y += bf_hi(u1.z);
            accB.z += bf_lo(u1.w); accB.w += bf_hi(u1.w);
        }
        if (jfull < cnt) {
            int q0 = jfull + grp, q1 = jfull + 8 + grp;
            int m0 = __shfl(idx, q0);
            int m1 = __shfl(idx, q1);
            float f0 = (q0 < cnt) ? 1.f : 0.f; if (q0 >= cnt) m0 = 0;
            float f1 = (q1 < cnt) ? 1.f : 0.f; if (q1 >= cnt) m1 = 0;
            uint4 u0 = Xb4[(size_t)m0 * 8 + col8];
            uint4 u1 = Xb4[(size_t)m1 * 8 + col8];
            accA.x += f0 * bf_lo(u0.x); accA.y += f0 * bf_hi(u0.x);
            accA.z += f0 * bf_lo(u0.y); accA.w += f0 * bf_hi(u0.y);
            accB.x += f0 * bf_lo(u0.z); accB.y += f0 * bf_hi(u0.z);
            accB.z += f0 * bf_lo(u0.w); accB.w += f0 * bf_hi(u0.w);
            accA.x += f1 * bf_lo(u1.x); accA.y += f1 * bf_hi(u1.x);
            accA.z += f1 * bf_lo(u1.y); accA.w += f1 * bf_hi(u1.y);
            accB.x += f1 * bf_lo(u1.z); accB.y += f1 * bf_hi(u1.z);
            accB.z += f1 * bf_lo(u1.w); accB.w += f1 * bf_hi(u1.w);
        }
    }
    #pragma unroll
    for (int d = 8; d < 64; d <<= 1) {
        accA.x += __shfl_xor(accA.x, d); accA.y += __shfl_xor(accA.y, d);
        accA.z += __shfl_xor(accA.z, d); accA.w += __shfl_xor(accA.w, d);
        accB.x += __shfl_xor(accB.x, d); accB.y += __shfl_xor(accB.y, d);
        accB.z += __shfl_xor(accB.z, d); accB.w += __shfl_xor(accB.w, d);
    }
    if (grp == 0) {
        int deg = s1 - s0;
        float inv = 1.f / (float)max(deg, 1);
        float4 r0 = make_float4(accA.x * inv, accA.y * inv, accA.z * inv, accA.w * inv);
        float4 r1 = make_float4(accB.x * inv, accB.y * inv, accB.z * inv, accB.w * inv);
        ((float4*)agg)[(size_t)node * 16 + col8 * 2]     = r0;
        ((float4*)agg)[(size_t)node * 16 + col8 * 2 + 1] = r1;
    }
}

// ---------------------------------------------------------------------------
// K5a: X2 = relu(X·Wself + agg·Wneigh + b). Weights in LDS; 4 threads/node.
// In-place X2-over-agg safe (node's 4 threads share one wave).
// ---------------------------------------------------------------------------
__global__ __launch_bounds__(256) void k_phaseA(const float* __restrict__ X,
                                                const float* agg,
                                                const float* __restrict__ Ws,
                                                const float* __restrict__ Wn,
                                                const float* __restrict__ bconv,
                                                float* X2, int N) {
    __shared__ float sWs[4096];
    __shared__ float sWn[4096];
    __shared__ float sb[64];
    int tid = threadIdx.x;
    for (int i = tid; i < 4096; i += 256) {
        sWs[i] = Ws[i];
        sWn[i] = Wn[i];
    }
    if (tid < 64) sb[tid] = bconv[tid];
    __syncthreads();

    int n = blockIdx.x * 64 + (tid >> 2);
    if (n >= N) return;
    int wb = (tid & 3) << 2;
    const float4* ws4 = (const float4*)sWs;
    const float4* wn4 = (const float4*)sWn;
    const float4* bv  = (const float4*)sb;
    const float4* Xv  = (const float4*)(X + (size_t)n * NHID);
    const float4* Gv  = (const float4*)(agg + (size_t)n * NHID);
    float4 a0 = bv[wb], a1 = bv[wb + 1], a2 = bv[wb + 2], a3 = bv[wb + 3];
    #pragma unroll 2
    for (int q = 0; q < 16; ++q) {
        float4 xq = Xv[q];
        float4 gq = Gv[q];
        float xs[4] = {xq.x, xq.y, xq.z, xq.w};
        float gs[4] = {gq.x, gq.y, gq.z, gq.w};
        #pragma unroll
        for (int j = 0; j < 4; ++j) {
            int k16 = (4 * q + j) * 16 + wb;
            float4 w0 = ws4[k16], w1 = ws4[k16 + 1], w2 = ws4[k16 + 2], w3 = ws4[k16 + 3];
            float4 m0 = wn4[k16], m1 = wn4[k16 + 1], m2 = wn4[k16 + 2], m3 = wn4[k16 + 3];
            float xj = xs[j], gj = gs[j];
            a0.x += xj * w0.x + gj * m0.x; a0.y += xj * w0.y + gj * m0.y;
            a0.z += xj * w0.z + gj * m0.z; a0.w += xj * w0.w + gj * m0.w;
            a1.x += xj * w1.x + gj * m1.x; a1.y += xj * w1.y + gj * m1.y;
            a1.z += xj * w1.z + gj * m1.z; a1.w += xj * w1.w + gj * m1.w;
            a2.x += xj * w2.x + gj * m2.x; a2.y += xj * w2.y + gj * m2.y;
            a2.z += xj * w2.z + gj * m2.z; a2.w += xj * w2.w + gj * m2.w;
            a3.x += xj * w3.x + gj * m3.x; a3.y += xj * w3.y + gj * m3.y;
            a3.z += xj * w3.z + gj * m3.z; a3.w += xj * w3.w + gj * m3.w;
        }
    }
    float4* out = (float4*)(X2 + (size_t)n * NHID);
    out[wb]     = make_float4(fmaxf(a0.x, 0.f), fmaxf(a0.y, 0.f), fmaxf(a0.z, 0.f), fmaxf(a0.w, 0.f));
    out[wb + 1] = make_float4(fmaxf(a1.x, 0.f), fmaxf(a1.y, 0.f), fmaxf(a1.z, 0.f), fmaxf(a1.w, 0.f));
    out[wb + 2] = make_float4(fmaxf(a2.x, 0.f), fmaxf(a2.y, 0.f), fmaxf(a2.z, 0.f), fmaxf(a2.w, 0.f));
    out[wb + 3] = make_float4(fmaxf(a3.x, 0.f), fmaxf(a3.y, 0.f), fmaxf(a3.z, 0.f), fmaxf(a3.w, 0.f));
}

// ---------------------------------------------------------------------------
// K_rp: one-shot repack of Qw into W2[64][128] = [A|B] row-major.
// ---------------------------------------------------------------------------
__global__ __launch_bounds__(256) void k_repackB(const float* __restrict__ Qw,
                                                 float* __restrict__ W2) {
    int i = blockIdx.x * 256 + threadIdx.x;   // grid covers 8192
    if (i >= 8192) return;
    int f = i >> 7, c = i & 127;
    float v;
    if (c < 64) v = Qw[(c >> 4) * 2048 + f * 16 + (c & 15)];
    else { int cc = c - 64; v = Qw[(cc >> 4) * 2048 + (64 + f) * 16 + (cc & 15)]; }
    W2[i] = v;
}

// ---------------------------------------------------------------------------
// K5b: [a|b] = X2 · W2 (+[Qb|0]). W2 in LDS. 8 threads/node.
// a written f32; b written PACKED BF16 (gather side of k_final).
// ---------------------------------------------------------------------------
__global__ __launch_bounds__(256) void k_phaseB(const float* __restrict__ X2,
                                                const float* __restrict__ W2,
                                                const float* __restrict__ Qb,
                                                float* __restrict__ aOut,
                                                unsigned* __restrict__ bOut, int N) {
    __shared__ float sW[8192];
    int tid = threadIdx.x;
    for (int i = tid; i < 8192; i += 256) sW[i] = W2[i];
    __syncthreads();

    int n = blockIdx.x * 32 + (tid >> 3);
    if (n >= N) return;
    int part = tid & 7;                 // 0..3 -> a cols, 4..7 -> b cols
    int wb = part << 2;                 // float4 base within 32-float4 row
    const float4* w4 = (const float4*)sW;
    float4 a0, a1, a2, a3;
    if (part < 4) {
        const float4* qv = (const float4*)Qb;
        a0 = qv[wb]; a1 = qv[wb + 1]; a2 = qv[wb + 2]; a3 = qv[wb + 3];
    } else {
        a0 = a1 = a2 = a3 = make_float4(0.f, 0.f, 0.f, 0.f);
    }
    const float4* Xv = (const float4*)(X2 + (size_t)n * NHID);
    #pragma unroll 2
    for (int q = 0; q < 16; ++q) {
        float4 xq = Xv[q];
        float xs[4] = {xq.x, xq.y, xq.z, xq.w};
        #pragma unroll
        for (int j = 0; j < 4; ++j) {
            int f32b = (4 * q + j) * 32 + wb;
            float4 w0 = w4[f32b], w1 = w4[f32b + 1], w2 = w4[f32b + 2], w3 = w4[f32b + 3];
            float xj = xs[j];
            a0.x += xj * w0.x; a0.y += xj * w0.y; a0.z += xj * w0.z; a0.w += xj * w0.w;
            a1.x += xj * w1.x; a1.y += xj * w1.y; a1.z += xj * w1.z; a1.w += xj * w1.w;
            a2.x += xj * w2.x; a2.y += xj * w2.y; a2.z += xj * w2.z; a2.w += xj * w2.w;
            a3.x += xj * w3.x; a3.y += xj * w3.y; a3.z += xj * w3.z; a3.w += xj * w3.w;
        }
    }
    if (part < 4) {
        float4* outp = (float4*)(aOut + (size_t)n * NHID) + wb;
        outp[0] = a0; outp[1] = a1; outp[2] = a2; outp[3] = a3;
    } else {
        uint4 p0, p1;
        p0.x = f2bf(a0.x) | (f2bf(a0.y) << 16);
        p0.y = f2bf(a0.z) | (f2bf(a0.w) << 16);
        p0.z = f2bf(a1.x) | (f2bf(a1.y) << 16);
        p0.w = f2bf(a1.z) | (f2bf(a1.w) << 16);
        p1.x = f2bf(a2.x) | (f2bf(a2.y) << 16);
        p1.y = f2bf(a2.z) | (f2bf(a2.w) << 16);
        p1.z = f2bf(a3.x) | (f2bf(a3.y) << 16);
        p1.w = f2bf(a3.z) | (f2bf(a3.w) << 16);
        uint4* outp = (uint4*)bOut + (size_t)n * 8 + (part - 4) * 2;
        outp[0] = p0; outp[1] = p1;
    }
}

// ---------------------------------------------------------------------------
// K6: gg[n,:] = tanh(mean over out-edges of (a[n,:] + b[dst,:])^2)
// b rows are bf16 (128B = 1 line); same 8x8 structure as K4.
// ---------------------------------------------------------------------------
__global__ __launch_bounds__(256) void k_final(const float* __restrict__ aF,
                                               const unsigned* __restrict__ bFb,
                                               const int* __restrict__ off_src,
                                               const int* __restrict__ csr_src,
                                               float* __restrict__ out, int N) {
    int lane = threadIdx.x & 63;
    int node = blockIdx.x * 4 + (threadIdx.x >> 6);
    if (node >= N) return;
    int grp = lane >> 3, col8 = lane & 7;
    const uint4* Bv = (const uint4*)bFb;
    const float4* Av = (const float4*)aF;
    float4 avA = Av[(size_t)node * 16 + col8 * 2];
    float4 avB = Av[(size_t)node * 16 + col8 * 2 + 1];
    int s0 = off_src[node], s1 = off_src[node + 1];
    float4 accA = make_float4(0.f, 0.f, 0.f, 0.f);
    float4 accB = make_float4(0.f, 0.f, 0.f, 0.f);
    for (int base = s0; base < s1; base += 64) {
        int cnt = min(64, s1 - base);
        int idx = (base + lane < s1) ? csr_src[base + lane] : 0;
        int jfull = cnt & ~15;
        for (int j = 0; j < jfull; j += 16) {
            int m0 = __shfl(idx, j + grp);
            int m1 = __shfl(idx, j + 8 + grp);
            uint4 u0 = Bv[(size_t)m0 * 8 + col8];
            uint4 u1 = Bv[(size_t)m1 * 8 + col8];
            float t;
            t = avA.x + bf_lo(u0.x); accA.x += t * t;
            t = avA.y + bf_hi(u0.x); accA.y += t * t;
            t = avA.z + bf_lo(u0.y); accA.z += t * t;
            t = avA.w + bf_hi(u0.y); accA.w += t * t;
            t = avB.x + bf_lo(u0.z); accB.x += t * t;
            t = avB.y + bf_hi(u0.z); accB.y += t * t;
            t = avB.z + bf_lo(u0.w); accB.z += t * t;
            t = avB.w + bf_hi(u0.w); accB.w += t * t;
            t = avA.x + bf_lo(u1.x); accA.x += t * t;
            t = avA.y + bf_hi(u1.x); accA.y += t * t;
            t = avA.z + bf_lo(u1.y); accA.z += t * t;
            t = avA.w + bf_hi(u1.y); accA.w += t * t;
            t = avB.x + bf_lo(u1.z); accB.x += t * t;
            t = avB.y + bf_hi(u1.z); accB.y += t * t;
            t = avB.z + bf_lo(u1.w); accB.z += t * t;
            t = avB.w + bf_hi(u1.w); accB.w += t * t;
        }
        if (jfull < cnt) {
            int q0 = jfull + grp, q1 = jfull + 8 + grp;
            int m0 = __shfl(idx, q0);
            int m1 = __shfl(idx, q1);
            float f0 = (q0 < cnt) ? 1.f : 0.f; if (q0 >= cnt) m0 = 0;
            float f1 = (q1 < cnt) ? 1.f : 0.f; if (q1 >= cnt) m1 = 0;
            uint4 u0 = Bv[(size_t)m0 * 8 + col8];
            uint4 u1 = Bv[(size_t)m1 * 8 + col8];
            float t;
            t = avA.x + bf_lo(u0.x); accA.x += f0 * t * t;
            t = avA.y + bf_hi(u0.x); accA.y += f0 * t * t;
            t = avA.z + bf_lo(u0.y); accA.z += f0 * t * t;
            t = avA.w + bf_hi(u0.y); accA.w += f0 * t * t;
            t = avB.x + bf_lo(u0.z); accB.x += f0 * t * t;
            t = avB.y + bf_hi(u0.z); accB.y += f0 * t * t;
            t = avB.z + bf_lo(u0.w); accB.z += f0 * t * t;
            t = avB.w + bf_hi(u0.w); accB.w += f0 * t * t;
            t = avA.x + bf_lo(u1.x); accA.x += f1 * t * t;
            t = avA.y + bf_hi(u1.x); accA.y += f1 * t * t;
            t = avA.z + bf_lo(u1.y); accA.z += f1 * t * t;
            t = avA.w + bf_hi(u1.y); accA.w += f1 * t * t;
            t = avB.x + bf_lo(u1.z); accB.x += f1 * t * t;
            t = avB.y + bf_hi(u1.z); accB.y += f1 * t * t;
            t = avB.z + bf_lo(u1.w); accB.z += f1 * t * t;
            t = avB.w + bf_hi(u1.w); accB.w += f1 * t * t;
        }
    }
    #pragma unroll
    for (int d = 8; d < 64; d <<= 1) {
        accA.x += __shfl_xor(accA.x, d); accA.y += __shfl_xor(accA.y, d);
        accA.z += __shfl_xor(accA.z, d); accA.w += __shfl_xor(accA.w, d);
        accB.x += __shfl_xor(accB.x, d); accB.y += __shfl_xor(accB.y, d);
        accB.z += __shfl_xor(accB.z, d); accB.w += __shfl_xor(accB.w, d);
    }
    if (grp == 0) {
        int deg = s1 - s0;
        float inv = 1.f / (float)max(deg, 1);
        float4 r0 = make_float4(tanhf(accA.x * inv), tanhf(accA.y * inv),
                                tanhf(accA.z * inv), tanhf(accA.w * inv));
        float4 r1 = make_float4(tanhf(accB.x * inv), tanhf(accB.y * inv),
                                tanhf(accB.z * inv), tanhf(accB.w * inv));
        ((float4*)out)[(size_t)node * 16 + col8 * 2]     = r0;
        ((float4*)out)[(size_t)node * 16 + col8 * 2 + 1] = r1;
    }
}

// ---------------------------------------------------------------------------
extern "C" void kernel_launch(void* const* d_in, const int* in_sizes, int n_in,
                              void* d_out, int out_size, void* d_ws, size_t ws_size,
                              hipStream_t stream) {
    const float* X      = (const float*)d_in[0];
    const int*   ei     = (const int*)d_in[1];
    const float* Wself  = (const float*)d_in[2];
    const float* Wneigh = (const float*)d_in[3];
    const float* bconv  = (const float*)d_in[4];
    const float* Qw     = (const float*)d_in[5];
    const float* Qb     = (const float*)d_in[6];

    int N = in_sizes[0] / NHID;
    int E = in_sizes[1] / 2;
    const int* src = ei;        // edge_index[0]
    const int* dst = ei + E;    // edge_index[1]
    int nB = (N + NPB - 1) >> NPB_SHIFT;           // 196 for N=100K
    int nChunks = (E + CHUNK - 1) / CHUNK;         // 391 for E=3.2M

    // ---- workspace layout (~103 MB) ----
    char* ws = (char*)d_ws;
    size_t bufBytes = (size_t)MAXB * CAP * 4;      // 21.0 MB per side
    size_t NH4 = (size_t)N * NHID * 4;             // 25.6 MB
    size_t NH2 = (size_t)N * NHID * 2;             // 12.8 MB
    unsigned int* buf0 = (unsigned int*)(ws);
    unsigned int* buf1 = (unsigned int*)(ws + bufBytes);
    float*    aggF = (float*)(ws);                              // after build
    float*    aF   = (float*)(ws + NH4);
    unsigned* bFb  = (unsigned*)(ws + 2 * NH4);                 // bf16 rows
    unsigned* Xb   = (unsigned*)(ws + 2 * NH4 + NH2);           // bf16 rows
    size_t pos = 3 * NH4;                                       // 76.8 MB
    if (pos < 2 * bufBytes) pos = 2 * bufBytes;
    pos = (pos + 255) & ~(size_t)255;
    auto alloc = [&](size_t bytes) -> void* {
        void* p = ws + pos;
        pos = (pos + bytes + 255) & ~(size_t)255;
        return p;
    };
    int* csr0   = (int*)alloc((size_t)E * 4);      // by dst
    int* csr1   = (int*)alloc((size_t)E * 4);      // by src
    int* off0   = (int*)alloc((size_t)(N + 1) * 4);
    int* off1   = (int*)alloc((size_t)(N + 1) * 4);
    int* btail0 = (int*)alloc((size_t)MAXB * 4);
    int* btail1 = (int*)alloc((size_t)MAXB * 4);
    int* boff0  = (int*)alloc((size_t)MAXB * 4);
    int* boff1  = (int*)alloc((size_t)MAXB * 4);
    float* W2   = (float*)alloc((size_t)8192 * 4); // repacked [A|B], 32KB
    (void)ws_size; (void)n_in; (void)out_size;

    hipMemsetAsync(btail0, 0, (size_t)2 * MAXB * 4, stream);   // btail0+btail1 contiguous

    k_bucketA<<<nChunks * 2, 256, 0, stream>>>(src, dst, buf0, buf1, btail0, btail1,
                                               E, nB, nChunks);
    k_bscan<<<1, 256, 0, stream>>>(btail0, btail1, boff0, boff1, off0, off1, nB, N);
    k_repackB<<<32, 256, 0, stream>>>(Qw, W2);
    k_xcast<<<(N * 8 + 255) / 256, 256, 0, stream>>>(X, Xb, N * 8);
    k_bucket_csr<<<nB * 2, 512, 0, stream>>>(buf0, buf1, btail0, btail1,
                                             boff0, boff1, off0, off1, csr0, csr1, N);
    k_agg<<<(N + 3) / 4, 256, 0, stream>>>(Xb, off0, csr0, aggF, N);
    k_phaseA<<<(N + 63) / 64, 256, 0, stream>>>(X, aggF, Wself, Wneigh, bconv, aggF, N);
    k_phaseB<<<(N + 31) / 32, 256, 0, stream>>>(aggF, W2, Qb, aF, bFb, N);
    k_final<<<(N + 3) / 4, 256, 0, stream>>>(aF, bFb, off1, csr1, (float*)d_out, N);
}